// Round 1
// baseline (577.908 us; speedup 1.0000x reference)
//
#include <hip/hip_runtime.h>
#include <cstdint>

#define NCLS 3
#define NPTS 100000
#define NB 2
#define PRE 512
#define POST 100
#define SCORE_TH 0.1f
#define NMS_TH 0.25

// ---------------- ws layout (bytes) ----------------
// keys       : uint32 [6*NPTS]        @ 0         (2,400,000)
// cand_idx   : uint32 [6*PRE]         @ 2,400,000 (12,288)
// cand_score : float  [6*PRE]         @ 2,412,288 (12,288)
// boxdata    : double [6*PRE*20]      @ 2,424,576 (491,520)
// mask       : uint64 [6*PRE*8]       @ 2,916,096 (196,608)
// total ~3.12 MB

// boxdata per candidate (20 doubles):
// [0]=x [1]=y [2]=cos [3]=sin [4]=hx [5]=hy [6]=zlo [7]=zhi [8]=vol [9]=rad
// [10..13]=corner x (CCW, ref order) [14..17]=corner y

__global__ __launch_bounds__(512) void topk_kernel(
    const float* __restrict__ cls, const float* __restrict__ boxes,
    uint32_t* __restrict__ keys, uint32_t* __restrict__ cand_idx,
    float* __restrict__ cand_score, double* __restrict__ boxdata)
{
    const int p = blockIdx.x;            // 0..5 = b*3 + k
    const int b = p / NCLS, k = p % NCLS;
    const int tid = threadIdx.x;
    uint32_t* pk = keys + (size_t)p * NPTS;

    // Pass 1: sigmoid (f64 -> f32), threshold, monotonic uint32 key
    for (int i = tid; i < NPTS; i += 512) {
        float x = cls[((size_t)b * NPTS + i) * NCLS + k];
        double sd = 1.0 / (1.0 + exp(-(double)x));
        float s = (float)sd;
        if (!(s >= SCORE_TH)) s = -1.0f;
        uint32_t u = __float_as_uint(s);
        uint32_t kk = (u & 0x80000000u) ? ~u : (u | 0x80000000u);
        pk[i] = kk;
    }
    __threadfence_block();
    __syncthreads();

    // Radix-select the PRE-th largest 64-bit key (keys are all distinct:
    // low 32 bits are ~index).
    __shared__ unsigned int hist[256];
    __shared__ uint64_t sprefix;
    __shared__ int srem;
    if (tid == 0) { sprefix = 0; srem = PRE; }
    __syncthreads();

    for (int byte = 7; byte >= 0; --byte) {
        for (int d = tid; d < 256; d += 512) hist[d] = 0;
        __syncthreads();
        const uint64_t prefix = sprefix;
        const int sh = byte * 8;
        for (int i = tid; i < NPTS; i += 512) {
            uint64_t key = ((uint64_t)pk[i] << 32) | (uint32_t)(~(uint32_t)i);
            bool ok = (byte == 7) ? true
                                  : ((key >> (sh + 8)) == (prefix >> (sh + 8)));
            if (ok) atomicAdd(&hist[(unsigned)((key >> sh) & 255)], 1u);
        }
        __syncthreads();
        if (tid == 0) {
            int r = srem;
            for (int d = 255; d >= 0; --d) {
                if ((int)hist[d] >= r) {
                    sprefix = prefix | ((uint64_t)d << sh);
                    srem = r;
                    break;
                }
                r -= (int)hist[d];
            }
        }
        __syncthreads();
    }

    // Collect the exactly-PRE keys >= pivot, bitonic sort descending
    __shared__ uint64_t skey[PRE];
    __shared__ int scol;
    if (tid == 0) scol = 0;
    __syncthreads();
    const uint64_t pivot = sprefix;
    for (int i = tid; i < NPTS; i += 512) {
        uint64_t key = ((uint64_t)pk[i] << 32) | (uint32_t)(~(uint32_t)i);
        if (key >= pivot) {
            int slot = atomicAdd(&scol, 1);
            if (slot < PRE) skey[slot] = key;
        }
    }
    __syncthreads();

    for (int k2 = 2; k2 <= PRE; k2 <<= 1)
        for (int j = k2 >> 1; j > 0; j >>= 1) {
            __syncthreads();
            int ixj = tid ^ j;
            if (ixj > tid) {
                uint64_t a = skey[tid], c = skey[ixj];
                bool up = ((tid & k2) == 0);
                bool sw = up ? (a < c) : (a > c);   // overall descending
                if (sw) { skey[tid] = c; skey[ixj] = a; }
            }
        }
    __syncthreads();

    // Epilogue: decode, stash candidate + precomputed f64 geometry
    {
        uint64_t key = skey[tid];
        uint32_t idx = ~((uint32_t)key);
        uint32_t ov = (uint32_t)(key >> 32);
        uint32_t ub = (ov & 0x80000000u) ? (ov ^ 0x80000000u) : ~ov;
        float sc = __uint_as_float(ub);
        cand_idx[p * PRE + tid] = idx;
        cand_score[p * PRE + tid] = sc;

        const float* bp = boxes + ((size_t)b * NPTS + idx) * 7;
        double x = bp[0], y = bp[1], z = bp[2];
        double dx = bp[3], dy = bp[4], dz = bp[5], r = bp[6];
        double c = cos(r), s = sin(r);
        double hx = 0.5 * dx, hy = 0.5 * dy;
        double* D = boxdata + (size_t)(p * PRE + tid) * 20;
        D[0] = x; D[1] = y; D[2] = c; D[3] = s; D[4] = hx; D[5] = hy;
        D[6] = z - 0.5 * dz; D[7] = z + 0.5 * dz;
        D[8] = dx * dy * dz;
        D[9] = sqrt(hx * hx + hy * hy);
        const double lxs[4] = { hx, -hx, -hx,  hx };
        const double lys[4] = { hy,  hy, -hy, -hy };
        #pragma unroll
        for (int m = 0; m < 4; ++m) {
            D[10 + m] = x + lxs[m] * c - lys[m] * s;
            D[14 + m] = y + lxs[m] * s + lys[m] * c;
        }
    }
}

__device__ double bev_inter(const double* __restrict__ A,
                            const double* __restrict__ B)
{
    double px[24], py[24];
    int cnt = 0;
    double sx = 0.0, sy = 0.0;

    // corners of A inside B (same collection order as the reference)
    #pragma unroll
    for (int m = 0; m < 4; ++m) {
        double cx = A[10 + m], cy = A[14 + m];
        double rx = cx - B[0], ry = cy - B[1];
        double u =  rx * B[2] + ry * B[3];
        double v = -rx * B[3] + ry * B[2];
        if (fabs(u) <= B[4] + 1e-5 && fabs(v) <= B[5] + 1e-5) {
            px[cnt] = cx; py[cnt] = cy; sx += cx; sy += cy; ++cnt;
        }
    }
    // corners of B inside A
    #pragma unroll
    for (int m = 0; m < 4; ++m) {
        double cx = B[10 + m], cy = B[14 + m];
        double rx = cx - A[0], ry = cy - A[1];
        double u =  rx * A[2] + ry * A[3];
        double v = -rx * A[3] + ry * A[2];
        if (fabs(u) <= A[4] + 1e-5 && fabs(v) <= A[5] + 1e-5) {
            px[cnt] = cx; py[cnt] = cy; sx += cx; sy += cy; ++cnt;
        }
    }
    // edge-pair intersections
    #pragma unroll
    for (int m = 0; m < 4; ++m) {
        double ax = A[10 + m], ay = A[14 + m];
        double rax = A[10 + ((m + 1) & 3)] - ax;
        double ray = A[14 + ((m + 1) & 3)] - ay;
        #pragma unroll
        for (int n = 0; n < 4; ++n) {
            double bx = B[10 + n], by = B[14 + n];
            double rbx = B[10 + ((n + 1) & 3)] - bx;
            double rby = B[14 + ((n + 1) & 3)] - by;
            double d = rax * rby - ray * rbx;
            if (fabs(d) > 1e-8) {
                double qx = bx - ax, qy = by - ay;
                double t  = (qx * rby - qy * rbx) / d;
                double uu = (qx * ray - qy * rax) / d;
                if (t >= 0.0 && t <= 1.0 && uu >= 0.0 && uu <= 1.0) {
                    double ix = ax + t * rax, iy = ay + t * ray;
                    px[cnt] = ix; py[cnt] = iy; sx += ix; sy += iy; ++cnt;
                }
            }
        }
    }

    if (cnt < 3) return 0.0;
    double cx = sx / cnt, cy = sy / cnt;
    double ang[24];
    for (int t = 0; t < cnt; ++t) ang[t] = atan2(py[t] - cy, px[t] - cx);
    // stable insertion sort by angle (same tie order as reference argsort)
    for (int t = 1; t < cnt; ++t) {
        double a = ang[t], X = px[t], Y = py[t];
        int q = t - 1;
        while (q >= 0 && ang[q] > a) {
            ang[q + 1] = ang[q]; px[q + 1] = px[q]; py[q + 1] = py[q]; --q;
        }
        ang[q + 1] = a; px[q + 1] = X; py[q + 1] = Y;
    }
    double area = 0.0;
    for (int t = 0; t < cnt; ++t) {
        int nt = (t + 1 == cnt) ? 0 : t + 1;
        area += (px[t] - cx) * (py[nt] - cy) - (py[t] - cy) * (px[nt] - cx);
    }
    return 0.5 * fabs(area);
}

__device__ bool iou_gt(const double* __restrict__ A,
                       const double* __restrict__ B)
{
    double zt = fmin(A[7], B[7]);
    double zb = fmax(A[6], B[6]);
    double hz = zt - zb;
    if (hz <= 0.0) return false;                 // i3 == 0 -> iou == 0
    double ddx = A[0] - B[0], ddy = A[1] - B[1];
    double rs = A[9] + B[9] + 1e-4;              // slack-safe bounding circles
    if (ddx * ddx + ddy * ddy > rs * rs) return false;
    double inter = bev_inter(A, B);
    double i3 = inter * hz;
    double den = A[8] + B[8] - i3;
    if (den < 1e-8) den = 1e-8;
    return (i3 / den) > (double)NMS_TH;
}

__global__ __launch_bounds__(256) void iou_kernel(
    const double* __restrict__ boxdata, unsigned long long* __restrict__ mask)
{
    int p = blockIdx.x * 256 + threadIdx.x;      // exactly 6*512*512 threads
    int prob = p >> 18;
    int rr = p & ((1 << 18) - 1);
    int i = rr >> 9, j = rr & 511;
    const double* A = boxdata + (size_t)(prob * PRE + i) * 20;
    const double* B = boxdata + (size_t)(prob * PRE + j) * 20;
    bool pred = (i == j) ? true : iou_gt(A, B);
    unsigned long long m = __ballot(pred);       // 64-bit on CDNA
    if ((threadIdx.x & 63) == 0)
        mask[(size_t)(prob * PRE + i) * 8 + (j >> 6)] = m;
}

__global__ __launch_bounds__(256) void nms_out_kernel(
    const float* __restrict__ boxes, const uint32_t* __restrict__ cand_idx,
    const float* __restrict__ cand_score,
    const unsigned long long* __restrict__ mask, float* __restrict__ out)
{
    const int p = blockIdx.x;
    const int b = p / NCLS, k = p % NCLS;
    const int tid = threadIdx.x;

    __shared__ unsigned long long smask[PRE * 8];   // 32 KB
    __shared__ float sscore[PRE];
    __shared__ int slist[POST];
    __shared__ int scnt;

    for (int w = tid; w < PRE * 8; w += 256)
        smask[w] = mask[(size_t)p * PRE * 8 + w];
    for (int i = tid; i < PRE; i += 256)
        sscore[i] = cand_score[p * PRE + i];
    __syncthreads();

    if (tid == 0) {
        unsigned long long sup[8] = {0, 0, 0, 0, 0, 0, 0, 0};
        int c = 0;
        for (int i = 0; i < PRE; ++i) {
            bool keep = (sscore[i] >= SCORE_TH) &&
                        !((sup[i >> 6] >> (i & 63)) & 1ull);
            if (keep) {
                if (c < POST) slist[c] = i;
                ++c;
                #pragma unroll
                for (int w = 0; w < 8; ++w) sup[w] |= smask[i * 8 + w];
            }
        }
        scnt = c;
    }
    __syncthreads();

    const int cnt = scnt;
    for (int t = tid; t < POST; t += 256) {
        int row = b * (NCLS * POST) + k * POST + t;         // 0..599
        float* ob = out + (size_t)row * 7;
        float* os = out + (size_t)NB * NCLS * POST * 7 + row;
        float* ol = out + (size_t)NB * NCLS * POST * 7 + (size_t)NB * NCLS * POST + row;
        if (t < cnt) {
            int r = slist[t];
            uint32_t idx = cand_idx[p * PRE + r];
            const float* bp = boxes + ((size_t)b * NPTS + idx) * 7;
            #pragma unroll
            for (int c7 = 0; c7 < 7; ++c7) ob[c7] = bp[c7];
            *os = sscore[r];
            *ol = (float)(k + 1);
        } else {
            #pragma unroll
            for (int c7 = 0; c7 < 7; ++c7) ob[c7] = 0.0f;
            *os = 0.0f;
            *ol = 0.0f;
        }
    }
}

extern "C" void kernel_launch(void* const* d_in, const int* in_sizes, int n_in,
                              void* d_out, int out_size, void* d_ws, size_t ws_size,
                              hipStream_t stream)
{
    (void)in_sizes; (void)n_in; (void)out_size; (void)ws_size;
    const float* cls   = (const float*)d_in[0];   // (2,100000,3) f32
    const float* boxes = (const float*)d_in[1];   // (2,100000,7) f32
    float* out = (float*)d_out;

    char* ws = (char*)d_ws;
    uint32_t* keys       = (uint32_t*)(ws);
    uint32_t* cand_idx   = (uint32_t*)(ws + 2400000);
    float*    cand_score = (float*)   (ws + 2412288);
    double*   boxdata    = (double*)  (ws + 2424576);
    unsigned long long* mask = (unsigned long long*)(ws + 2916096);

    hipLaunchKernelGGL(topk_kernel, dim3(NB * NCLS), dim3(512), 0, stream,
                       cls, boxes, keys, cand_idx, cand_score, boxdata);
    hipLaunchKernelGGL(iou_kernel, dim3((NB * NCLS * PRE * PRE) / 256), dim3(256),
                       0, stream, boxdata, mask);
    hipLaunchKernelGGL(nms_out_kernel, dim3(NB * NCLS), dim3(256), 0, stream,
                       boxes, cand_idx, cand_score, mask, out);
}

// Round 2
// 369.991 us; speedup vs baseline: 1.5620x; 1.5620x over previous
//
#include <hip/hip_runtime.h>
#include <cstdint>

#define NCLS 3
#define NPTS 100000
#define NB 2
#define PRE 512
#define POST 100
#define SCORE_TH 0.1f
#define NMS_TH 0.25
#define CAP 2048            // candidate buffer per problem (pivot bin ~200 elems for this data)
#define BPP 98              // blocks per batch for elementwise kernels (98*1024 >= 100000)

// ---------------- ws layout (bytes) ----------------
// keys      : uint32 [6*NPTS]       @ 0          (2,400,000)
// hist      : uint32 [6*65536]      @ 2,400,000  (1,572,864)   \ zeroed by one
// cand_cnt  : uint32 [6] (pad 64)   @ 3,972,864  (64)          / hipMemsetAsync
// pivots    : uint32 [6] (pad 64)   @ 3,972,928  (64)
// cand      : uint64 [6*CAP]        @ 3,972,992  (98,304)
// cand_idx  : uint32 [6*PRE]        @ 4,071,296  (12,288)
// cand_scr  : float  [6*PRE]        @ 4,083,584  (12,288)
// boxdata   : double [6*PRE*20]     @ 4,095,872  (491,520)
// screen    : float  [6*PRE*8]      @ 4,587,392  (98,304)
// mask      : uint64 [6*PRE*8]      @ 4,685,696  (196,608)
// total ~4.88 MB

// boxdata per candidate (20 doubles):
// [0]=x [1]=y [2]=cos [3]=sin [4]=hx [5]=hy [6]=zlo [7]=zhi [8]=vol [9]=rad
// [10..13]=corner x (ref order) [14..17]=corner y
// screen per candidate (8 floats): [0]=x [1]=y [2]=zlo [3]=zhi [4]=rad

__device__ __forceinline__ uint32_t score_key(float x)
{
    // f64 sigmoid rounded to f32 == reference (verified absmax 0.0 in R1)
    double sd = 1.0 / (1.0 + exp(-(double)x));
    float s = (float)sd;
    if (!(s >= SCORE_TH)) s = -1.0f;
    uint32_t u = __float_as_uint(s);
    return (u & 0x80000000u) ? ~u : (u | 0x80000000u);
}

__global__ __launch_bounds__(256) void key_hist_kernel(
    const float* __restrict__ cls, uint32_t* __restrict__ keys,
    uint32_t* __restrict__ hist)
{
    const int blk = blockIdx.x;           // 0 .. NB*BPP-1
    const int b = blk / BPP, cb = blk % BPP;
    const int base = cb * 1024;
    for (int t = threadIdx.x; t < 1024; t += 256) {
        int i = base + t;
        if (i >= NPTS) continue;
        const float* cp = cls + ((size_t)b * NPTS + i) * NCLS;
        #pragma unroll
        for (int k = 0; k < NCLS; ++k) {
            uint32_t kk = score_key(cp[k]);
            int p = b * NCLS + k;
            keys[(size_t)p * NPTS + i] = kk;
            atomicAdd(&hist[(size_t)p * 65536 + (kk >> 16)], 1u);
        }
    }
}

__global__ __launch_bounds__(256) void pivot_kernel(
    const uint32_t* __restrict__ hist, uint32_t* __restrict__ pivots)
{
    const int p = blockIdx.x;
    const int tid = threadIdx.x;
    const uint32_t* H = hist + (size_t)p * 65536;
    __shared__ uint32_t csum[256];
    uint32_t s = 0;
    const int b0 = tid * 256;
    for (int bi = b0; bi < b0 + 256; ++bi) s += H[bi];
    csum[tid] = s;
    __syncthreads();
    if (tid == 0) {
        int cum = 0, cchunk = 0;
        for (int c = 255; c >= 0; --c) {
            if (cum + (int)csum[c] >= PRE) { cchunk = c; break; }
            cum += (int)csum[c];
        }
        uint32_t pb = 0;
        for (int bin = cchunk * 256 + 255; bin >= cchunk * 256; --bin) {
            int h = (int)H[bin];
            if (cum + h >= PRE) { pb = (uint32_t)bin; break; }
            cum += h;
        }
        pivots[p] = pb;
    }
}

__global__ __launch_bounds__(256) void compact_kernel(
    const uint32_t* __restrict__ keys, const uint32_t* __restrict__ pivots,
    uint32_t* __restrict__ cand_cnt, unsigned long long* __restrict__ cand)
{
    const int blk = blockIdx.x;
    const int b = blk / BPP, cb = blk % BPP;
    const int base = cb * 1024;
    uint32_t pb[NCLS];
    #pragma unroll
    for (int k = 0; k < NCLS; ++k) pb[k] = pivots[b * NCLS + k];
    for (int t = threadIdx.x; t < 1024; t += 256) {
        int i = base + t;
        if (i >= NPTS) continue;
        #pragma unroll
        for (int k = 0; k < NCLS; ++k) {
            int p = b * NCLS + k;
            uint32_t kk = keys[(size_t)p * NPTS + i];
            if ((kk >> 16) >= pb[k]) {
                unsigned int slot = atomicAdd(&cand_cnt[p], 1u);
                if (slot < CAP) {
                    unsigned long long key =
                        ((unsigned long long)kk << 32) | (uint32_t)(~(uint32_t)i);
                    cand[(size_t)p * CAP + slot] = key;
                }
            }
        }
    }
}

__global__ __launch_bounds__(512) void select_kernel(
    const float* __restrict__ boxes, const unsigned long long* __restrict__ cand,
    const uint32_t* __restrict__ cand_cnt, uint32_t* __restrict__ cand_idx,
    float* __restrict__ cand_score, double* __restrict__ boxdata,
    float* __restrict__ screen)
{
    const int p = blockIdx.x;
    const int b = p / NCLS;
    const int tid = threadIdx.x;
    __shared__ unsigned long long skey[CAP];
    const int cnt = min((int)cand_cnt[p], CAP);
    for (int i = tid; i < CAP; i += 512)
        skey[i] = (i < cnt) ? cand[(size_t)p * CAP + i] : 0ull;
    __syncthreads();

    // bitonic sort, overall descending (all keys distinct; 0-padding sinks)
    for (int kk = 2; kk <= CAP; kk <<= 1)
        for (int j = kk >> 1; j > 0; j >>= 1) {
            for (int i = tid; i < CAP; i += 512) {
                int ixj = i ^ j;
                if (ixj > i) {
                    unsigned long long a = skey[i], c = skey[ixj];
                    bool up = ((i & kk) == 0);
                    if (up ? (a < c) : (a > c)) { skey[i] = c; skey[ixj] = a; }
                }
            }
            __syncthreads();
        }

    // epilogue: top-512 decode + f64 geometry + f32 screen
    unsigned long long key = skey[tid];
    double* D = boxdata + (size_t)(p * PRE + tid) * 20;
    float* S = screen + (size_t)(p * PRE + tid) * 8;
    if (key == 0ull) {                     // defensive: can't happen normally
        cand_idx[p * PRE + tid] = 0;
        cand_score[p * PRE + tid] = -1.0f;
        #pragma unroll
        for (int m = 0; m < 20; ++m) D[m] = 0.0;
        #pragma unroll
        for (int m = 0; m < 8; ++m) S[m] = 0.0f;
        return;
    }
    uint32_t idx = ~((uint32_t)key);
    uint32_t ov = (uint32_t)(key >> 32);
    uint32_t ub = (ov & 0x80000000u) ? (ov ^ 0x80000000u) : ~ov;
    float sc = __uint_as_float(ub);
    cand_idx[p * PRE + tid] = idx;
    cand_score[p * PRE + tid] = sc;

    const float* bp = boxes + ((size_t)b * NPTS + idx) * 7;
    double x = bp[0], y = bp[1], z = bp[2];
    double dx = bp[3], dy = bp[4], dz = bp[5], r = bp[6];
    double c = cos(r), s = sin(r);
    double hx = 0.5 * dx, hy = 0.5 * dy;
    double zlo = z - 0.5 * dz, zhi = z + 0.5 * dz;
    double rad = sqrt(hx * hx + hy * hy);
    D[0] = x; D[1] = y; D[2] = c; D[3] = s; D[4] = hx; D[5] = hy;
    D[6] = zlo; D[7] = zhi; D[8] = dx * dy * dz; D[9] = rad;
    const double lxs[4] = { hx, -hx, -hx,  hx };
    const double lys[4] = { hy,  hy, -hy, -hy };
    #pragma unroll
    for (int m = 0; m < 4; ++m) {
        D[10 + m] = x + lxs[m] * c - lys[m] * s;
        D[14 + m] = y + lxs[m] * s + lys[m] * c;
    }
    S[0] = (float)x; S[1] = (float)y; S[2] = (float)zlo; S[3] = (float)zhi;
    S[4] = (float)rad; S[5] = 0.0f; S[6] = 0.0f; S[7] = 0.0f;
}

__device__ double bev_inter(const double* __restrict__ A,
                            const double* __restrict__ B)
{
    double px[24], py[24];
    int cnt = 0;
    double sx = 0.0, sy = 0.0;

    #pragma unroll
    for (int m = 0; m < 4; ++m) {
        double cx = A[10 + m], cy = A[14 + m];
        double rx = cx - B[0], ry = cy - B[1];
        double u =  rx * B[2] + ry * B[3];
        double v = -rx * B[3] + ry * B[2];
        if (fabs(u) <= B[4] + 1e-5 && fabs(v) <= B[5] + 1e-5) {
            px[cnt] = cx; py[cnt] = cy; sx += cx; sy += cy; ++cnt;
        }
    }
    #pragma unroll
    for (int m = 0; m < 4; ++m) {
        double cx = B[10 + m], cy = B[14 + m];
        double rx = cx - A[0], ry = cy - A[1];
        double u =  rx * A[2] + ry * A[3];
        double v = -rx * A[3] + ry * A[2];
        if (fabs(u) <= A[4] + 1e-5 && fabs(v) <= A[5] + 1e-5) {
            px[cnt] = cx; py[cnt] = cy; sx += cx; sy += cy; ++cnt;
        }
    }
    #pragma unroll
    for (int m = 0; m < 4; ++m) {
        double ax = A[10 + m], ay = A[14 + m];
        double rax = A[10 + ((m + 1) & 3)] - ax;
        double ray = A[14 + ((m + 1) & 3)] - ay;
        #pragma unroll
        for (int n = 0; n < 4; ++n) {
            double bx = B[10 + n], by = B[14 + n];
            double rbx = B[10 + ((n + 1) & 3)] - bx;
            double rby = B[14 + ((n + 1) & 3)] - by;
            double d = rax * rby - ray * rbx;
            if (fabs(d) > 1e-8) {
                double qx = bx - ax, qy = by - ay;
                double t  = (qx * rby - qy * rbx) / d;
                double uu = (qx * ray - qy * rax) / d;
                if (t >= 0.0 && t <= 1.0 && uu >= 0.0 && uu <= 1.0) {
                    double ix = ax + t * rax, iy = ay + t * ray;
                    px[cnt] = ix; py[cnt] = iy; sx += ix; sy += iy; ++cnt;
                }
            }
        }
    }

    if (cnt < 3) return 0.0;
    double cx = sx / cnt, cy = sy / cnt;
    double ang[24];
    for (int t = 0; t < cnt; ++t) ang[t] = atan2(py[t] - cy, px[t] - cx);
    for (int t = 1; t < cnt; ++t) {
        double a = ang[t], X = px[t], Y = py[t];
        int q = t - 1;
        while (q >= 0 && ang[q] > a) {
            ang[q + 1] = ang[q]; px[q + 1] = px[q]; py[q + 1] = py[q]; --q;
        }
        ang[q + 1] = a; px[q + 1] = X; py[q + 1] = Y;
    }
    double area = 0.0;
    for (int t = 0; t < cnt; ++t) {
        int nt = (t + 1 == cnt) ? 0 : t + 1;
        area += (px[t] - cx) * (py[nt] - cy) - (py[t] - cy) * (px[nt] - cx);
    }
    return 0.5 * fabs(area);
}

__device__ bool iou_gt_slow(const double* __restrict__ A,
                            const double* __restrict__ B)
{
    double zt = fmin(A[7], B[7]);
    double zb = fmax(A[6], B[6]);
    double hz = zt - zb;
    if (hz <= 0.0) return false;
    double inter = bev_inter(A, B);
    double i3 = inter * hz;
    double den = A[8] + B[8] - i3;
    if (den < 1e-8) den = 1e-8;
    return (i3 / den) > (double)NMS_TH;
}

__global__ __launch_bounds__(256) void iou_kernel(
    const double* __restrict__ boxdata, const float* __restrict__ screen,
    unsigned long long* __restrict__ mask)
{
    int p = blockIdx.x * 256 + threadIdx.x;      // exactly 6*512*512 threads
    int prob = p >> 18;
    int rr = p & ((1 << 18) - 1);
    int i = rr >> 9, j = rr & 511;
    bool pred = false;
    if (j > i) {                                  // lower-triangle bits never read
        const float* SA = screen + (size_t)(prob * PRE + i) * 8;
        const float* SB = screen + (size_t)(prob * PRE + j) * 8;
        float4 a4 = *(const float4*)SA;           // x,y,zlo,zhi
        float4 b4 = *(const float4*)SB;
        float hz = fminf(a4.w, b4.w) - fmaxf(a4.z, b4.z);
        if (hz > 0.0f) {
            float ddx = a4.x - b4.x, ddy = a4.y - b4.y;
            float rs = SA[4] + SB[4] + 0.01f;     // slack >> f32 rounding error
            if (ddx * ddx + ddy * ddy <= rs * rs) {
                const double* A = boxdata + (size_t)(prob * PRE + i) * 20;
                const double* B = boxdata + (size_t)(prob * PRE + j) * 20;
                pred = iou_gt_slow(A, B);
            }
        }
    }
    unsigned long long m = __ballot(pred);
    if ((threadIdx.x & 63) == 0)
        mask[(size_t)(prob * PRE + i) * 8 + (j >> 6)] = m;
}

__global__ __launch_bounds__(256) void nms_out_kernel(
    const float* __restrict__ boxes, const uint32_t* __restrict__ cand_idx,
    const float* __restrict__ cand_score,
    const unsigned long long* __restrict__ mask, float* __restrict__ out)
{
    const int p = blockIdx.x;
    const int b = p / NCLS, k = p % NCLS;
    const int tid = threadIdx.x;

    __shared__ unsigned long long smask[PRE * 8];   // 32 KB
    __shared__ float sscore[PRE];
    __shared__ int slist[POST];
    __shared__ int scnt;

    for (int w = tid; w < PRE * 8; w += 256)
        smask[w] = mask[(size_t)p * PRE * 8 + w];
    for (int i = tid; i < PRE; i += 256)
        sscore[i] = cand_score[p * PRE + i];
    __syncthreads();

    if (tid == 0) {
        unsigned long long sup[8] = {0, 0, 0, 0, 0, 0, 0, 0};
        int c = 0;
        for (int i = 0; i < PRE; ++i) {
            bool keep = (sscore[i] >= SCORE_TH) &&
                        !((sup[i >> 6] >> (i & 63)) & 1ull);
            if (keep) {
                if (c < POST) slist[c] = i;
                ++c;
                #pragma unroll
                for (int w = 0; w < 8; ++w) sup[w] |= smask[i * 8 + w];
            }
        }
        scnt = c;
    }
    __syncthreads();

    const int cnt = scnt;
    for (int t = tid; t < POST; t += 256) {
        int row = b * (NCLS * POST) + k * POST + t;         // 0..599
        float* ob = out + (size_t)row * 7;
        float* os = out + (size_t)NB * NCLS * POST * 7 + row;
        float* ol = out + (size_t)NB * NCLS * POST * 7 + (size_t)NB * NCLS * POST + row;
        if (t < cnt) {
            int r = slist[t];
            uint32_t idx = cand_idx[p * PRE + r];
            const float* bp = boxes + ((size_t)b * NPTS + idx) * 7;
            #pragma unroll
            for (int c7 = 0; c7 < 7; ++c7) ob[c7] = bp[c7];
            *os = sscore[r];
            *ol = (float)(k + 1);
        } else {
            #pragma unroll
            for (int c7 = 0; c7 < 7; ++c7) ob[c7] = 0.0f;
            *os = 0.0f;
            *ol = 0.0f;
        }
    }
}

extern "C" void kernel_launch(void* const* d_in, const int* in_sizes, int n_in,
                              void* d_out, int out_size, void* d_ws, size_t ws_size,
                              hipStream_t stream)
{
    (void)in_sizes; (void)n_in; (void)out_size; (void)ws_size;
    const float* cls   = (const float*)d_in[0];   // (2,100000,3) f32
    const float* boxes = (const float*)d_in[1];   // (2,100000,7) f32
    float* out = (float*)d_out;

    char* ws = (char*)d_ws;
    uint32_t* keys        = (uint32_t*)(ws);
    uint32_t* hist        = (uint32_t*)(ws + 2400000);
    uint32_t* cand_cnt    = (uint32_t*)(ws + 3972864);
    uint32_t* pivots      = (uint32_t*)(ws + 3972928);
    unsigned long long* cand = (unsigned long long*)(ws + 3972992);
    uint32_t* cand_idx    = (uint32_t*)(ws + 4071296);
    float*    cand_score  = (float*)   (ws + 4083584);
    double*   boxdata     = (double*)  (ws + 4095872);
    float*    screen      = (float*)   (ws + 4587392);
    unsigned long long* mask = (unsigned long long*)(ws + 4685696);

    // zero hist + cand_cnt (ws is poisoned 0xAA before every call)
    hipMemsetAsync(hist, 0, 1572864 + 64, stream);

    hipLaunchKernelGGL(key_hist_kernel, dim3(NB * BPP), dim3(256), 0, stream,
                       cls, keys, hist);
    hipLaunchKernelGGL(pivot_kernel, dim3(NB * NCLS), dim3(256), 0, stream,
                       hist, pivots);
    hipLaunchKernelGGL(compact_kernel, dim3(NB * BPP), dim3(256), 0, stream,
                       keys, pivots, cand_cnt, cand);
    hipLaunchKernelGGL(select_kernel, dim3(NB * NCLS), dim3(512), 0, stream,
                       boxes, cand, cand_cnt, cand_idx, cand_score, boxdata, screen);
    hipLaunchKernelGGL(iou_kernel, dim3((NB * NCLS * PRE * PRE) / 256), dim3(256),
                       0, stream, boxdata, screen, mask);
    hipLaunchKernelGGL(nms_out_kernel, dim3(NB * NCLS), dim3(256), 0, stream,
                       boxes, cand_idx, cand_score, mask, out);
}

// Round 4
// 291.093 us; speedup vs baseline: 1.9853x; 1.2710x over previous
//
#include <hip/hip_runtime.h>
#include <cstdint>

#define NCLS 3
#define NPTS 100000
#define NB 2
#define PRE 512
#define POST 100
#define SCORE_TH 0.1f
#define NMS_TH 0.25
#define CAP 1024            // candidate buffer per problem (pivot bin ~80 elems)
#define BPP 98              // blocks per batch (98*1024 >= 100000)
#define NBINS 768           // 16-bit key bins offset by 0xBD00 cover all s>=0.1
#define BIN_OFF 0xBD00
#define MAXPAIRS 262144
#define NPROB (NB * NCLS)
#define WAVES_PER_PROB 2304  // 36 upper-tri 64x64 cells x 64 rows

// ---------------- ws layout (bytes) ----------------
// [memset 0 region: 0 .. 215168)
// hist      : uint32 [6*768]        @ 0          (18,432)
// cand_cnt  : uint32 [6] (pad 64)   @ 18,432
// pair_cnt  : uint32 [1] (pad 64)   @ 18,496
// mask      : uint64 [6*PRE*8]      @ 18,560     (196,608)
// [not memset]
// pivots    : uint32 [6] (pad 64)   @ 215,168
// cand      : uint64 [6*CAP]        @ 215,232    (49,152)
// cand_idx  : uint32 [6*PRE]        @ 264,384    (12,288)
// cand_scr  : float  [6*PRE]        @ 276,672    (12,288)
// boxdata   : double [6*PRE*20]     @ 288,960    (491,520)
// screen    : float  [6*PRE*8]      @ 780,480    (98,304)
// pairs     : uint32 [MAXPAIRS]     @ 878,784    (1,048,576)
// total ~1.93 MB

// boxdata per candidate (20 doubles):
// [0]=x [1]=y [2]=cos [3]=sin [4]=hx [5]=hy [6]=zlo [7]=zhi [8]=vol [9]=rad
// [10..13]=corner x (ref order) [14..17]=corner y
// screen per candidate (8 floats): [0]=x [1]=y [2]=zlo [3]=zhi [4]=rad

__device__ __forceinline__ uint32_t score_key(float x)
{
    // f64 sigmoid rounded to f32 == reference (verified absmax 0.0 R1/R2)
    double sd = 1.0 / (1.0 + exp(-(double)x));
    float s = (float)sd;
    if (!(s >= SCORE_TH)) s = -1.0f;
    uint32_t u = __float_as_uint(s);
    return (u & 0x80000000u) ? ~u : (u | 0x80000000u);
}

__device__ __forceinline__ int key_bin(uint32_t kk)
{
    int idx = (int)(kk >> 16) - BIN_OFF;
    if (idx < 0) idx = 0;
    if (idx > NBINS - 1) idx = NBINS - 1;
    return idx;
}

__global__ __launch_bounds__(256) void hist_kernel(
    const float* __restrict__ cls, uint32_t* __restrict__ hist)
{
    const int blk = blockIdx.x;           // 0 .. NB*BPP-1
    const int b = blk / BPP, cb = blk % BPP;
    const int base = cb * 1024;
    for (int t = threadIdx.x; t < 1024; t += 256) {
        int i = base + t;
        if (i >= NPTS) continue;
        const float* cp = cls + ((size_t)b * NPTS + i) * NCLS;
        #pragma unroll
        for (int k = 0; k < NCLS; ++k) {
            uint32_t kk = score_key(cp[k]);
            atomicAdd(&hist[(b * NCLS + k) * NBINS + key_bin(kk)], 1u);
        }
    }
}

__global__ __launch_bounds__(256) void pivot_kernel(
    const uint32_t* __restrict__ hist, uint32_t* __restrict__ pivots)
{
    const int p = blockIdx.x;
    const int tid = threadIdx.x;
    const uint32_t* H = hist + p * NBINS;
    __shared__ uint32_t csum[256];
    uint32_t s = 0;
    #pragma unroll
    for (int b = 0; b < 3; ++b) s += H[tid * 3 + b];
    csum[tid] = s;
    __syncthreads();
    if (tid == 0) {
        int cum = 0, cchunk = 0;
        for (int c = 255; c >= 0; --c) {
            if (cum + (int)csum[c] >= PRE) { cchunk = c; break; }
            cum += (int)csum[c];
        }
        uint32_t pb = 0;
        for (int bin = cchunk * 3 + 2; bin >= cchunk * 3; --bin) {
            int h = (int)H[bin];
            if (cum + h >= PRE) { pb = (uint32_t)bin; break; }
            cum += h;
        }
        pivots[p] = pb;
    }
}

__global__ __launch_bounds__(256) void compact_kernel(
    const float* __restrict__ cls, const uint32_t* __restrict__ pivots,
    uint32_t* __restrict__ cand_cnt, unsigned long long* __restrict__ cand)
{
    const int blk = blockIdx.x;
    const int b = blk / BPP, cb = blk % BPP;
    const int base = cb * 1024;
    uint32_t pb[NCLS];
    #pragma unroll
    for (int k = 0; k < NCLS; ++k) pb[k] = pivots[b * NCLS + k];
    for (int t = threadIdx.x; t < 1024; t += 256) {
        int i = base + t;
        if (i >= NPTS) continue;
        const float* cp = cls + ((size_t)b * NPTS + i) * NCLS;
        #pragma unroll
        for (int k = 0; k < NCLS; ++k) {
            uint32_t kk = score_key(cp[k]);
            if ((uint32_t)key_bin(kk) >= pb[k]) {
                int p = b * NCLS + k;
                unsigned int slot = atomicAdd(&cand_cnt[p], 1u);
                if (slot < CAP) {
                    unsigned long long key =
                        ((unsigned long long)kk << 32) | (uint32_t)(~(uint32_t)i);
                    cand[(size_t)p * CAP + slot] = key;
                }
            }
        }
    }
}

__global__ __launch_bounds__(512) void select_kernel(
    const float* __restrict__ boxes, const unsigned long long* __restrict__ cand,
    const uint32_t* __restrict__ cand_cnt, uint32_t* __restrict__ cand_idx,
    float* __restrict__ cand_score, double* __restrict__ boxdata,
    float* __restrict__ screen)
{
    const int p = blockIdx.x;
    const int b = p / NCLS;
    const int tid = threadIdx.x;
    __shared__ unsigned long long skey[CAP];
    const int cnt = min((int)cand_cnt[p], CAP);
    for (int i = tid; i < CAP; i += 512)
        skey[i] = (i < cnt) ? cand[(size_t)p * CAP + i] : 0ull;
    __syncthreads();

    // bitonic sort, overall descending (all keys distinct; 0-padding sinks)
    for (int k2 = 2; k2 <= CAP; k2 <<= 1)
        for (int j = k2 >> 1; j > 0; j >>= 1) {
            for (int i = tid; i < CAP; i += 512) {
                int ixj = i ^ j;
                if (ixj > i) {
                    unsigned long long a = skey[i], c = skey[ixj];
                    bool up = ((i & k2) == 0);
                    if (up ? (a < c) : (a > c)) { skey[i] = c; skey[ixj] = a; }
                }
            }
            __syncthreads();
        }

    // epilogue: top-512 decode + f64 geometry + f32 screen
    if (tid >= PRE) return;
    unsigned long long key = skey[tid];
    double* D = boxdata + (size_t)(p * PRE + tid) * 20;
    float* S = screen + (size_t)(p * PRE + tid) * 8;
    if (key == 0ull) {                     // defensive: can't happen normally
        cand_idx[p * PRE + tid] = 0;
        cand_score[p * PRE + tid] = -1.0f;
        #pragma unroll
        for (int m = 0; m < 20; ++m) D[m] = 0.0;
        #pragma unroll
        for (int m = 0; m < 8; ++m) S[m] = 0.0f;
        return;
    }
    uint32_t idx = ~((uint32_t)key);
    uint32_t ov = (uint32_t)(key >> 32);
    uint32_t ub = (ov & 0x80000000u) ? (ov ^ 0x80000000u) : ~ov;
    float sc = __uint_as_float(ub);
    cand_idx[p * PRE + tid] = idx;
    cand_score[p * PRE + tid] = sc;

    const float* bp = boxes + ((size_t)b * NPTS + idx) * 7;
    double x = bp[0], y = bp[1], z = bp[2];
    double dx = bp[3], dy = bp[4], dz = bp[5], r = bp[6];
    double c = cos(r), s = sin(r);
    double hx = 0.5 * dx, hy = 0.5 * dy;
    double zlo = z - 0.5 * dz, zhi = z + 0.5 * dz;
    double rad = sqrt(hx * hx + hy * hy);
    D[0] = x; D[1] = y; D[2] = c; D[3] = s; D[4] = hx; D[5] = hy;
    D[6] = zlo; D[7] = zhi; D[8] = dx * dy * dz; D[9] = rad;
    const double lxs[4] = { hx, -hx, -hx,  hx };
    const double lys[4] = { hy,  hy, -hy, -hy };
    #pragma unroll
    for (int m = 0; m < 4; ++m) {
        D[10 + m] = x + lxs[m] * c - lys[m] * s;
        D[14 + m] = y + lxs[m] * s + lys[m] * c;
    }
    S[0] = (float)x; S[1] = (float)y; S[2] = (float)zlo; S[3] = (float)zhi;
    S[4] = (float)rad; S[5] = 0.0f; S[6] = 0.0f; S[7] = 0.0f;
}

// Fast f32 triangle-only screen: append surviving (prob,i,j) pairs.
// Waves tile the upper triangle in 64x64 cells: 36 cells x 64 rows/problem.
// Grid MUST cover all NPROB problems: NPROB * WAVES_PER_PROB waves total
// (R3 bug: grid covered only 2 of 6 problems -> 4 classes unsuppressed).
__global__ __launch_bounds__(256) void screen_kernel(
    const float* __restrict__ screen, uint32_t* __restrict__ pair_cnt,
    uint32_t* __restrict__ pairs)
{
    int W = blockIdx.x * 4 + (threadIdx.x >> 6);
    int lane = threadIdx.x & 63;
    int prob = W / WAVES_PER_PROB;
    int t = W - prob * WAVES_PER_PROB;
    int cell = t >> 6, r = t & 63;
    int wi = 0;
    while (cell >= 8 - wi) { cell -= 8 - wi; ++wi; }
    int wj = wi + cell;
    int i = wi * 64 + r;
    int j = wj * 64 + lane;
    bool surv = false;
    if (j > i) {
        const float* SA = screen + (size_t)(prob * PRE + i) * 8;  // wave-uniform
        const float* SB = screen + (size_t)(prob * PRE + j) * 8;
        float4 a4 = *(const float4*)SA;           // x,y,zlo,zhi
        float4 b4 = *(const float4*)SB;
        float hz = fminf(a4.w, b4.w) - fmaxf(a4.z, b4.z);
        if (hz > 0.0f) {
            float ddx = a4.x - b4.x, ddy = a4.y - b4.y;
            float rs = SA[4] + SB[4] + 0.01f;     // slack >> f32 rounding error
            surv = (ddx * ddx + ddy * ddy <= rs * rs);
        }
    }
    if (surv) {
        uint32_t slot = atomicAdd(pair_cnt, 1u);
        if (slot < MAXPAIRS)
            pairs[slot] = ((uint32_t)prob << 20) | ((uint32_t)i << 10) | (uint32_t)j;
    }
}

__device__ double bev_inter(const double* __restrict__ A,
                            const double* __restrict__ B)
{
    double px[24], py[24];
    int cnt = 0;
    double sx = 0.0, sy = 0.0;

    #pragma unroll
    for (int m = 0; m < 4; ++m) {
        double cx = A[10 + m], cy = A[14 + m];
        double rx = cx - B[0], ry = cy - B[1];
        double u =  rx * B[2] + ry * B[3];
        double v = -rx * B[3] + ry * B[2];
        if (fabs(u) <= B[4] + 1e-5 && fabs(v) <= B[5] + 1e-5) {
            px[cnt] = cx; py[cnt] = cy; sx += cx; sy += cy; ++cnt;
        }
    }
    #pragma unroll
    for (int m = 0; m < 4; ++m) {
        double cx = B[10 + m], cy = B[14 + m];
        double rx = cx - A[0], ry = cy - A[1];
        double u =  rx * A[2] + ry * A[3];
        double v = -rx * A[3] + ry * A[2];
        if (fabs(u) <= A[4] + 1e-5 && fabs(v) <= A[5] + 1e-5) {
            px[cnt] = cx; py[cnt] = cy; sx += cx; sy += cy; ++cnt;
        }
    }
    #pragma unroll
    for (int m = 0; m < 4; ++m) {
        double ax = A[10 + m], ay = A[14 + m];
        double rax = A[10 + ((m + 1) & 3)] - ax;
        double ray = A[14 + ((m + 1) & 3)] - ay;
        #pragma unroll
        for (int n = 0; n < 4; ++n) {
            double bx = B[10 + n], by = B[14 + n];
            double rbx = B[10 + ((n + 1) & 3)] - bx;
            double rby = B[14 + ((n + 1) & 3)] - by;
            double d = rax * rby - ray * rbx;
            if (fabs(d) > 1e-8) {
                double qx = bx - ax, qy = by - ay;
                double t  = (qx * rby - qy * rbx) / d;
                double uu = (qx * ray - qy * rax) / d;
                if (t >= 0.0 && t <= 1.0 && uu >= 0.0 && uu <= 1.0) {
                    double ix = ax + t * rax, iy = ay + t * ray;
                    px[cnt] = ix; py[cnt] = iy; sx += ix; sy += iy; ++cnt;
                }
            }
        }
    }

    if (cnt < 3) return 0.0;
    double cx = sx / cnt, cy = sy / cnt;
    double ang[24];
    for (int t = 0; t < cnt; ++t) ang[t] = atan2(py[t] - cy, px[t] - cx);
    for (int t = 1; t < cnt; ++t) {
        double a = ang[t], X = px[t], Y = py[t];
        int q = t - 1;
        while (q >= 0 && ang[q] > a) {
            ang[q + 1] = ang[q]; px[q + 1] = px[q]; py[q + 1] = py[q]; --q;
        }
        ang[q + 1] = a; px[q + 1] = X; py[q + 1] = Y;
    }
    double area = 0.0;
    for (int t = 0; t < cnt; ++t) {
        int nt = (t + 1 == cnt) ? 0 : t + 1;
        area += (px[t] - cx) * (py[nt] - cy) - (py[t] - cy) * (px[nt] - cx);
    }
    return 0.5 * fabs(area);
}

__device__ bool iou_gt_slow(const double* __restrict__ A,
                            const double* __restrict__ B)
{
    double zt = fmin(A[7], B[7]);
    double zb = fmax(A[6], B[6]);
    double hz = zt - zb;
    if (hz <= 0.0) return false;
    double inter = bev_inter(A, B);
    double i3 = inter * hz;
    double den = A[8] + B[8] - i3;
    if (den < 1e-8) den = 1e-8;
    return (i3 / den) > (double)NMS_TH;
}

__global__ __launch_bounds__(256) void exact_kernel(
    const double* __restrict__ boxdata, const uint32_t* __restrict__ pairs,
    const uint32_t* __restrict__ pair_cnt, unsigned long long* __restrict__ mask)
{
    int n = (int)*pair_cnt;
    if (n > MAXPAIRS) n = MAXPAIRS;
    for (int idx = blockIdx.x * 256 + threadIdx.x; idx < n; idx += 256 * 256) {
        uint32_t code = pairs[idx];
        int prob = code >> 20;
        int i = (code >> 10) & 1023;
        int j = code & 1023;
        const double* A = boxdata + (size_t)(prob * PRE + i) * 20;
        const double* B = boxdata + (size_t)(prob * PRE + j) * 20;
        if (iou_gt_slow(A, B))
            atomicOr(&mask[(size_t)(prob * PRE + i) * 8 + (j >> 6)],
                     1ull << (j & 63));
    }
}

__global__ __launch_bounds__(256) void nms_out_kernel(
    const float* __restrict__ boxes, const uint32_t* __restrict__ cand_idx,
    const float* __restrict__ cand_score,
    const unsigned long long* __restrict__ mask, float* __restrict__ out)
{
    const int p = blockIdx.x;
    const int b = p / NCLS, k = p % NCLS;
    const int tid = threadIdx.x;

    __shared__ unsigned long long smask[PRE * 8];   // 32 KB
    __shared__ float sscore[PRE];
    __shared__ int slist[POST];
    __shared__ int scnt;

    for (int w = tid; w < PRE * 8; w += 256)
        smask[w] = mask[(size_t)p * PRE * 8 + w];
    for (int i = tid; i < PRE; i += 256)
        sscore[i] = cand_score[p * PRE + i];
    __syncthreads();

    // Wave-parallel greedy scan: lane l owns sup bits of columns w*64+l
    // (bit w of supbits). Early break at c==POST: later kept rows can never
    // reach the output (out loop caps at t < POST).
    if (tid < 64) {
        const int lane = tid;
        uint32_t supbits = 0;
        int c = 0;
        for (int i = 0; i < PRE; ++i) {
            uint32_t sb = (uint32_t)__shfl((int)supbits, i & 63);
            bool sup_i = (sb >> (i >> 6)) & 1u;
            float sc = sscore[i];                      // LDS broadcast
            bool keep = (sc >= SCORE_TH) && !sup_i;    // wave-uniform
            if (keep) {
                if (lane == 0) slist[c] = i;
                ++c;
                if (c >= POST) break;
                #pragma unroll
                for (int w = 0; w < 8; ++w) {
                    unsigned long long m = smask[i * 8 + w];  // broadcast
                    supbits |= (uint32_t)((m >> lane) & 1ull) << w;
                }
            }
        }
        if (lane == 0) scnt = c;
    }
    __syncthreads();

    const int cnt = scnt;
    for (int t = tid; t < POST; t += 256) {
        int row = b * (NCLS * POST) + k * POST + t;          // 0..599
        float* ob = out + (size_t)row * 7;
        float* os = out + (size_t)NB * NCLS * POST * 7 + row;
        float* ol = out + (size_t)NB * NCLS * POST * 7 + (size_t)NB * NCLS * POST + row;
        if (t < cnt) {
            int r = slist[t];
            uint32_t idx = cand_idx[p * PRE + r];
            const float* bp = boxes + ((size_t)b * NPTS + idx) * 7;
            #pragma unroll
            for (int c7 = 0; c7 < 7; ++c7) ob[c7] = bp[c7];
            *os = sscore[r];
            *ol = (float)(k + 1);
        } else {
            #pragma unroll
            for (int c7 = 0; c7 < 7; ++c7) ob[c7] = 0.0f;
            *os = 0.0f;
            *ol = 0.0f;
        }
    }
}

extern "C" void kernel_launch(void* const* d_in, const int* in_sizes, int n_in,
                              void* d_out, int out_size, void* d_ws, size_t ws_size,
                              hipStream_t stream)
{
    (void)in_sizes; (void)n_in; (void)out_size; (void)ws_size;
    const float* cls   = (const float*)d_in[0];   // (2,100000,3) f32
    const float* boxes = (const float*)d_in[1];   // (2,100000,7) f32
    float* out = (float*)d_out;

    char* ws = (char*)d_ws;
    uint32_t* hist        = (uint32_t*)(ws);
    uint32_t* cand_cnt    = (uint32_t*)(ws + 18432);
    uint32_t* pair_cnt    = (uint32_t*)(ws + 18496);
    unsigned long long* mask = (unsigned long long*)(ws + 18560);
    uint32_t* pivots      = (uint32_t*)(ws + 215168);
    unsigned long long* cand = (unsigned long long*)(ws + 215232);
    uint32_t* cand_idx    = (uint32_t*)(ws + 264384);
    float*    cand_score  = (float*)   (ws + 276672);
    double*   boxdata     = (double*)  (ws + 288960);
    float*    screen      = (float*)   (ws + 780480);
    uint32_t* pairs       = (uint32_t*)(ws + 878784);

    // zero hist + cand_cnt + pair_cnt + mask (ws poisoned 0xAA each call)
    hipMemsetAsync(ws, 0, 215168, stream);

    hipLaunchKernelGGL(hist_kernel, dim3(NB * BPP), dim3(256), 0, stream,
                       cls, hist);
    hipLaunchKernelGGL(pivot_kernel, dim3(NPROB), dim3(256), 0, stream,
                       hist, pivots);
    hipLaunchKernelGGL(compact_kernel, dim3(NB * BPP), dim3(256), 0, stream,
                       cls, pivots, cand_cnt, cand);
    hipLaunchKernelGGL(select_kernel, dim3(NPROB), dim3(512), 0, stream,
                       boxes, cand, cand_cnt, cand_idx, cand_score, boxdata, screen);
    hipLaunchKernelGGL(screen_kernel, dim3(NPROB * WAVES_PER_PROB / 4), dim3(256),
                       0, stream, screen, pair_cnt, pairs);
    hipLaunchKernelGGL(exact_kernel, dim3(256), dim3(256), 0, stream,
                       boxdata, pairs, pair_cnt, mask);
    hipLaunchKernelGGL(nms_out_kernel, dim3(NPROB), dim3(256), 0, stream,
                       boxes, cand_idx, cand_score, mask, out);
}

// Round 5
// 237.445 us; speedup vs baseline: 2.4339x; 1.2259x over previous
//
#include <hip/hip_runtime.h>
#include <cstdint>

#define NCLS 3
#define NPTS 100000
#define NB 2
#define PRE 512
#define POST 100
#define SCORE_TH 0.1f
#define NMS_TH 0.25
#define CAP 1024            // candidate buffer per problem (expect ~690)
#define BPP 98              // blocks per batch (98*1024 >= 100000)
#define NBINS 384           // fast-key bins: (key>>17) - (0xBD000000>>17)
#define BIN_SH 17
#define BIN_OFFW (0xBD000000u >> BIN_SH)
#define FMARG 2e-5f         // 2x bound on |f32 sigmoid - f64 sigmoid| (<=1e-6)
#define MAXPAIRS 262144
#define NPROB (NB * NCLS)
#define WAVES_PER_PROB 2304  // 36 upper-tri 64x64 cells x 64 rows

// ---------------- ws layout (bytes) ----------------
// [memset 0 region: 0 .. 205,952)
// hist      : uint32 [6*384]        @ 0          (9,216)
// cand_cnt  : uint32 [6] (pad 64)   @ 9,216
// pair_cnt  : uint32 [1] (pad 64)   @ 9,280
// mask      : uint64 [6*PRE*8]      @ 9,344      (196,608)
// [not memset]
// pivots    : uint32 [6] (pad 64)   @ 205,952
// cand      : uint64 [6*CAP]        @ 206,016    (49,152)
// cand_idx  : uint32 [6*PRE]        @ 255,168    (12,288)
// cand_scr  : float  [6*PRE]        @ 267,456    (12,288)
// boxdata   : double [6*PRE*20]     @ 279,744    (491,520)
// screen    : float  [6*PRE*8]      @ 771,264    (98,304)
// pairs     : uint32 [MAXPAIRS]     @ 869,568    (1,048,576)
// total ~1.92 MB

// boxdata per candidate (20 doubles):
// [0]=x [1]=y [2]=cos [3]=sin [4]=hx [5]=hy [6]=zlo [7]=zhi [8]=vol [9]=rad
// [10..13]=corner x (ref order) [14..17]=corner y
// screen per candidate (8 floats): [0]=x [1]=y [2]=zlo [3]=zhi [4]=rad

__device__ __forceinline__ uint32_t score_key(float x)
{
    // EXACT path: f64 sigmoid rounded to f32 == reference (absmax 0.0 R1-R4)
    double sd = 1.0 / (1.0 + exp(-(double)x));
    float s = (float)sd;
    if (!(s >= SCORE_TH)) s = -1.0f;
    uint32_t u = __float_as_uint(s);
    return (u & 0x80000000u) ? ~u : (u | 0x80000000u);
}

__device__ __forceinline__ float fast_sig(float x)
{
    return 1.0f / (1.0f + __expf(-x));
}

// monotone bin of a (possibly margin-adjusted) f32 score
__device__ __forceinline__ int fast_bin(float s)
{
    float v = (s >= SCORE_TH) ? s : -1.0f;
    uint32_t u = __float_as_uint(v);
    uint32_t kk = (u & 0x80000000u) ? ~u : (u | 0x80000000u);
    int b = (int)(kk >> BIN_SH) - (int)BIN_OFFW;
    return b < 0 ? 0 : (b > NBINS - 1 ? NBINS - 1 : b);
}

// LDS-first histogram: global atomic contention was 64 us in R4
// (600k atomics on 4.6k addresses); nonzero-only flush spreads it.
__global__ __launch_bounds__(256) void hist_kernel(
    const float* __restrict__ cls, uint32_t* __restrict__ hist)
{
    __shared__ uint32_t lh[NCLS * NBINS];
    for (int t = threadIdx.x; t < NCLS * NBINS; t += 256) lh[t] = 0;
    __syncthreads();
    const int b = blockIdx.x / BPP, cb = blockIdx.x % BPP;
    const int base = cb * 1024;
    for (int t = threadIdx.x; t < 1024; t += 256) {
        int i = base + t;
        if (i >= NPTS) continue;
        const float* cp = cls + ((size_t)b * NPTS + i) * NCLS;
        #pragma unroll
        for (int k = 0; k < NCLS; ++k)
            atomicAdd(&lh[k * NBINS + fast_bin(fast_sig(cp[k]))], 1u);
    }
    __syncthreads();
    for (int t = threadIdx.x; t < NCLS * NBINS; t += 256) {
        uint32_t c = lh[t];
        if (c)
            atomicAdd(&hist[(b * NCLS + t / NBINS) * NBINS + t % NBINS], c);
    }
}

__global__ __launch_bounds__(256) void pivot_kernel(
    const uint32_t* __restrict__ hist, uint32_t* __restrict__ pivots)
{
    const int p = blockIdx.x;
    const int tid = threadIdx.x;
    const uint32_t* H = hist + p * NBINS;
    __shared__ uint32_t csum[128];          // 3 bins per chunk
    if (tid < 128) {
        uint32_t s = 0;
        #pragma unroll
        for (int b = 0; b < 3; ++b) s += H[tid * 3 + b];
        csum[tid] = s;
    }
    __syncthreads();
    if (tid == 0) {
        int cum = 0, cchunk = 0;
        for (int c = 127; c >= 0; --c) {
            if (cum + (int)csum[c] >= PRE) { cchunk = c; break; }
            cum += (int)csum[c];
        }
        uint32_t pb = 0;
        for (int bin = cchunk * 3 + 2; bin >= cchunk * 3; --bin) {
            int h = (int)H[bin];
            if (cum + h >= PRE) { pb = (uint32_t)bin; break; }
            cum += h;
        }
        pivots[p] = pb;
    }
}

// Filter by fast bin with +2*FMARG slack (provable superset of exact
// top-512); exact f64 key computed only for the ~700/problem survivors.
__global__ __launch_bounds__(256) void compact_kernel(
    const float* __restrict__ cls, const uint32_t* __restrict__ pivots,
    uint32_t* __restrict__ cand_cnt, unsigned long long* __restrict__ cand)
{
    const int b = blockIdx.x / BPP, cb = blockIdx.x % BPP;
    const int base = cb * 1024;
    uint32_t pb[NCLS];
    #pragma unroll
    for (int k = 0; k < NCLS; ++k) pb[k] = pivots[b * NCLS + k];
    for (int t = threadIdx.x; t < 1024; t += 256) {
        int i = base + t;
        if (i >= NPTS) continue;
        const float* cp = cls + ((size_t)b * NPTS + i) * NCLS;
        #pragma unroll
        for (int k = 0; k < NCLS; ++k) {
            float sf = fast_sig(cp[k]);
            if ((uint32_t)fast_bin(sf + FMARG) >= pb[k]) {
                uint32_t kk = score_key(cp[k]);     // exact key
                int p = b * NCLS + k;
                unsigned int slot = atomicAdd(&cand_cnt[p], 1u);
                if (slot < CAP)
                    cand[(size_t)p * CAP + slot] =
                        ((unsigned long long)kk << 32) | (uint32_t)(~(uint32_t)i);
            }
        }
    }
}

__global__ __launch_bounds__(512) void select_kernel(
    const float* __restrict__ boxes, const unsigned long long* __restrict__ cand,
    const uint32_t* __restrict__ cand_cnt, uint32_t* __restrict__ cand_idx,
    float* __restrict__ cand_score, double* __restrict__ boxdata,
    float* __restrict__ screen)
{
    const int p = blockIdx.x;
    const int b = p / NCLS;
    const int tid = threadIdx.x;
    __shared__ unsigned long long skey[CAP];
    const int cnt = min((int)cand_cnt[p], CAP);
    for (int i = tid; i < CAP; i += 512)
        skey[i] = (i < cnt) ? cand[(size_t)p * CAP + i] : 0ull;
    __syncthreads();

    // bitonic sort, overall descending (all keys distinct; 0-padding sinks)
    for (int k2 = 2; k2 <= CAP; k2 <<= 1)
        for (int j = k2 >> 1; j > 0; j >>= 1) {
            for (int i = tid; i < CAP; i += 512) {
                int ixj = i ^ j;
                if (ixj > i) {
                    unsigned long long a = skey[i], c = skey[ixj];
                    bool up = ((i & k2) == 0);
                    if (up ? (a < c) : (a > c)) { skey[i] = c; skey[ixj] = a; }
                }
            }
            __syncthreads();
        }

    // epilogue: top-512 decode + f64 geometry + f32 screen
    if (tid >= PRE) return;
    unsigned long long key = skey[tid];
    double* D = boxdata + (size_t)(p * PRE + tid) * 20;
    float* S = screen + (size_t)(p * PRE + tid) * 8;
    if (key == 0ull) {                     // defensive: can't happen normally
        cand_idx[p * PRE + tid] = 0;
        cand_score[p * PRE + tid] = -1.0f;
        #pragma unroll
        for (int m = 0; m < 20; ++m) D[m] = 0.0;
        #pragma unroll
        for (int m = 0; m < 8; ++m) S[m] = 0.0f;
        return;
    }
    uint32_t idx = ~((uint32_t)key);
    uint32_t ov = (uint32_t)(key >> 32);
    uint32_t ub = (ov & 0x80000000u) ? (ov ^ 0x80000000u) : ~ov;
    float sc = __uint_as_float(ub);
    cand_idx[p * PRE + tid] = idx;
    cand_score[p * PRE + tid] = sc;

    const float* bp = boxes + ((size_t)b * NPTS + idx) * 7;
    double x = bp[0], y = bp[1], z = bp[2];
    double dx = bp[3], dy = bp[4], dz = bp[5], r = bp[6];
    double c = cos(r), s = sin(r);
    double hx = 0.5 * dx, hy = 0.5 * dy;
    double zlo = z - 0.5 * dz, zhi = z + 0.5 * dz;
    double rad = sqrt(hx * hx + hy * hy);
    D[0] = x; D[1] = y; D[2] = c; D[3] = s; D[4] = hx; D[5] = hy;
    D[6] = zlo; D[7] = zhi; D[8] = dx * dy * dz; D[9] = rad;
    const double lxs[4] = { hx, -hx, -hx,  hx };
    const double lys[4] = { hy,  hy, -hy, -hy };
    #pragma unroll
    for (int m = 0; m < 4; ++m) {
        D[10 + m] = x + lxs[m] * c - lys[m] * s;
        D[14 + m] = y + lxs[m] * s + lys[m] * c;
    }
    S[0] = (float)x; S[1] = (float)y; S[2] = (float)zlo; S[3] = (float)zhi;
    S[4] = (float)rad; S[5] = 0.0f; S[6] = 0.0f; S[7] = 0.0f;
}

// Fast f32 triangle-only screen: append surviving (prob,i,j) pairs.
__global__ __launch_bounds__(256) void screen_kernel(
    const float* __restrict__ screen, uint32_t* __restrict__ pair_cnt,
    uint32_t* __restrict__ pairs)
{
    int W = blockIdx.x * 4 + (threadIdx.x >> 6);
    int lane = threadIdx.x & 63;
    int prob = W / WAVES_PER_PROB;
    int t = W - prob * WAVES_PER_PROB;
    int cell = t >> 6, r = t & 63;
    int wi = 0;
    while (cell >= 8 - wi) { cell -= 8 - wi; ++wi; }
    int wj = wi + cell;
    int i = wi * 64 + r;
    int j = wj * 64 + lane;
    bool surv = false;
    if (j > i) {
        const float* SA = screen + (size_t)(prob * PRE + i) * 8;  // wave-uniform
        const float* SB = screen + (size_t)(prob * PRE + j) * 8;
        float4 a4 = *(const float4*)SA;           // x,y,zlo,zhi
        float4 b4 = *(const float4*)SB;
        float hz = fminf(a4.w, b4.w) - fmaxf(a4.z, b4.z);
        if (hz > 0.0f) {
            float ddx = a4.x - b4.x, ddy = a4.y - b4.y;
            float rs = SA[4] + SB[4] + 0.01f;     // slack >> f32 rounding error
            surv = (ddx * ddx + ddy * ddy <= rs * rs);
        }
    }
    if (surv) {
        uint32_t slot = atomicAdd(pair_cnt, 1u);
        if (slot < MAXPAIRS)
            pairs[slot] = ((uint32_t)prob << 20) | ((uint32_t)i << 10) | (uint32_t)j;
    }
}

// Wave-per-pair exact IoU: lane owns one candidate point of the reference
// construction (0-3 A-corners, 4-7 B-corners, 8-23 edge intersections).
// No per-thread arrays -> no scratch spill (R4's exact was 76us latency-bound
// on spilled px[24]/py[24]/ang[24] + insertion sort).
__global__ __launch_bounds__(256) void exact_kernel(
    const double* __restrict__ boxdata, const uint32_t* __restrict__ pairs,
    const uint32_t* __restrict__ pair_cnt, unsigned long long* __restrict__ mask)
{
    const int lane = threadIdx.x & 63;
    const int wave = (blockIdx.x * 256 + threadIdx.x) >> 6;
    const int nwaves = gridDim.x * 4;
    int n = (int)*pair_cnt;
    if (n > MAXPAIRS) n = MAXPAIRS;

    for (int pr = wave; pr < n; pr += nwaves) {
        uint32_t code = pairs[pr];
        int prob = code >> 20;
        int bi = (code >> 10) & 1023;
        int bj = code & 1023;
        const double* A = boxdata + (size_t)(prob * PRE + bi) * 20;
        const double* B = boxdata + (size_t)(prob * PRE + bj) * 20;

        double PX = 0.0, PY = 0.0;
        bool valid = false;
        if (lane < 8) {
            const double* S = (lane < 4) ? A : B;
            const double* O = (lane < 4) ? B : A;
            int m = lane & 3;
            PX = S[10 + m]; PY = S[14 + m];
            double rx = PX - O[0], ry = PY - O[1];
            double u =  rx * O[2] + ry * O[3];
            double v = -rx * O[3] + ry * O[2];
            valid = (fabs(u) <= O[4] + 1e-5) && (fabs(v) <= O[5] + 1e-5);
        } else if (lane < 24) {
            int e = lane - 8, m = e >> 2, nn = e & 3;
            double ax = A[10 + m], ay = A[14 + m];
            double rax = A[10 + ((m + 1) & 3)] - ax;
            double ray = A[14 + ((m + 1) & 3)] - ay;
            double bx = B[10 + nn], by = B[14 + nn];
            double rbx = B[10 + ((nn + 1) & 3)] - bx;
            double rby = B[14 + ((nn + 1) & 3)] - by;
            double d = rax * rby - ray * rbx;
            if (fabs(d) > 1e-8) {
                double qx = bx - ax, qy = by - ay;
                double t  = (qx * rby - qy * rbx) / d;
                double uu = (qx * ray - qy * rax) / d;
                valid = (t >= 0.0 && t <= 1.0 && uu >= 0.0 && uu <= 1.0);
                PX = ax + t * rax; PY = ay + t * ray;
            }
        }
        if (!valid) { PX = 0.0; PY = 0.0; }

        unsigned long long bal = __ballot(valid);
        int cnt = __popcll(bal);
        double sx = PX, sy = PY;          // invalid lanes contribute 0
        #pragma unroll
        for (int off = 32; off; off >>= 1) {
            sx += __shfl_xor(sx, off);
            sy += __shfl_xor(sy, off);
        }
        int cdiv = cnt > 0 ? cnt : 1;     // ref: / max(cnt, 1)
        double cxc = sx / cdiv, cyc = sy / cdiv;

        double ang = valid ? atan2(PY - cyc, PX - cxc) : 1e9;
        int sidx = lane;                  // construction order == ref slot order

        // 64-lane bitonic sort ascending by (ang, sidx) == numpy stable argsort
        #pragma unroll
        for (int k = 2; k <= 64; k <<= 1) {
            #pragma unroll
            for (int jj = k >> 1; jj > 0; jj >>= 1) {
                double oang = __shfl_xor(ang, jj);
                double opx  = __shfl_xor(PX, jj);
                double opy  = __shfl_xor(PY, jj);
                int    oidx = __shfl_xor(sidx, jj);
                bool iLow = (lane & jj) == 0;
                bool dirUp = (lane & k) == 0;
                bool mineFirst = (ang < oang) || (ang == oang && sidx < oidx);
                bool keepMine = (mineFirst == (iLow == dirUp));
                if (!keepMine) { ang = oang; PX = opx; PY = opy; sidx = oidx; }
            }
        }

        // centered shoelace over sorted lanes [0, cnt)
        double nxp = __shfl(PX, (lane + 1) & 63);
        double nyp = __shfl(PY, (lane + 1) & 63);
        double fx  = __shfl(PX, 0);
        double fy  = __shfl(PY, 0);
        bool last = (lane == cnt - 1);
        double qx = last ? fx : nxp, qy = last ? fy : nyp;
        double contrib = 0.0;
        if (lane < cnt)
            contrib = (PX - cxc) * (qy - cyc) - (PY - cyc) * (qx - cxc);
        #pragma unroll
        for (int off = 32; off; off >>= 1) contrib += __shfl_xor(contrib, off);
        double inter = (cnt >= 3) ? 0.5 * fabs(contrib) : 0.0;

        if (lane == 0) {
            double zt = fmin(A[7], B[7]);
            double zb = fmax(A[6], B[6]);
            double hz = zt - zb;
            bool sup = false;
            if (hz > 0.0) {
                double i3 = inter * hz;
                double den = A[8] + B[8] - i3;
                if (den < 1e-8) den = 1e-8;
                sup = (i3 / den) > (double)NMS_TH;
            }
            if (sup)
                atomicOr(&mask[(size_t)(prob * PRE + bi) * 8 + (bj >> 6)],
                         1ull << (bj & 63));
        }
    }
}

__global__ __launch_bounds__(256) void nms_out_kernel(
    const float* __restrict__ boxes, const uint32_t* __restrict__ cand_idx,
    const float* __restrict__ cand_score,
    const unsigned long long* __restrict__ mask, float* __restrict__ out)
{
    const int p = blockIdx.x;
    const int b = p / NCLS, k = p % NCLS;
    const int tid = threadIdx.x;

    __shared__ unsigned long long smask[PRE * 8];   // 32 KB
    __shared__ float sscore[PRE];
    __shared__ int slist[POST];
    __shared__ int scnt;

    for (int w = tid; w < PRE * 8; w += 256)
        smask[w] = mask[(size_t)p * PRE * 8 + w];
    for (int i = tid; i < PRE; i += 256)
        sscore[i] = cand_score[p * PRE + i];
    __syncthreads();

    // Wave-parallel greedy scan; early break at c==POST (later kept rows
    // can never reach the POST-capped output).
    if (tid < 64) {
        const int lane = tid;
        uint32_t supbits = 0;
        int c = 0;
        for (int i = 0; i < PRE; ++i) {
            uint32_t sb = (uint32_t)__shfl((int)supbits, i & 63);
            bool sup_i = (sb >> (i >> 6)) & 1u;
            float sc = sscore[i];                      // LDS broadcast
            bool keep = (sc >= SCORE_TH) && !sup_i;    // wave-uniform
            if (keep) {
                if (lane == 0) slist[c] = i;
                ++c;
                if (c >= POST) break;
                #pragma unroll
                for (int w = 0; w < 8; ++w) {
                    unsigned long long m = smask[i * 8 + w];  // broadcast
                    supbits |= (uint32_t)((m >> lane) & 1ull) << w;
                }
            }
        }
        if (lane == 0) scnt = c;
    }
    __syncthreads();

    const int cnt = scnt;
    for (int t = tid; t < POST; t += 256) {
        int row = b * (NCLS * POST) + k * POST + t;          // 0..599
        float* ob = out + (size_t)row * 7;
        float* os = out + (size_t)NB * NCLS * POST * 7 + row;
        float* ol = out + (size_t)NB * NCLS * POST * 7 + (size_t)NB * NCLS * POST + row;
        if (t < cnt) {
            int r = slist[t];
            uint32_t idx = cand_idx[p * PRE + r];
            const float* bp = boxes + ((size_t)b * NPTS + idx) * 7;
            #pragma unroll
            for (int c7 = 0; c7 < 7; ++c7) ob[c7] = bp[c7];
            *os = sscore[r];
            *ol = (float)(k + 1);
        } else {
            #pragma unroll
            for (int c7 = 0; c7 < 7; ++c7) ob[c7] = 0.0f;
            *os = 0.0f;
            *ol = 0.0f;
        }
    }
}

extern "C" void kernel_launch(void* const* d_in, const int* in_sizes, int n_in,
                              void* d_out, int out_size, void* d_ws, size_t ws_size,
                              hipStream_t stream)
{
    (void)in_sizes; (void)n_in; (void)out_size; (void)ws_size;
    const float* cls   = (const float*)d_in[0];   // (2,100000,3) f32
    const float* boxes = (const float*)d_in[1];   // (2,100000,7) f32
    float* out = (float*)d_out;

    char* ws = (char*)d_ws;
    uint32_t* hist        = (uint32_t*)(ws);
    uint32_t* cand_cnt    = (uint32_t*)(ws + 9216);
    uint32_t* pair_cnt    = (uint32_t*)(ws + 9280);
    unsigned long long* mask = (unsigned long long*)(ws + 9344);
    uint32_t* pivots      = (uint32_t*)(ws + 205952);
    unsigned long long* cand = (unsigned long long*)(ws + 206016);
    uint32_t* cand_idx    = (uint32_t*)(ws + 255168);
    float*    cand_score  = (float*)   (ws + 267456);
    double*   boxdata     = (double*)  (ws + 279744);
    float*    screen      = (float*)   (ws + 771264);
    uint32_t* pairs       = (uint32_t*)(ws + 869568);

    // zero hist + cand_cnt + pair_cnt + mask (ws poisoned 0xAA each call)
    hipMemsetAsync(ws, 0, 205952, stream);

    hipLaunchKernelGGL(hist_kernel, dim3(NB * BPP), dim3(256), 0, stream,
                       cls, hist);
    hipLaunchKernelGGL(pivot_kernel, dim3(NPROB), dim3(256), 0, stream,
                       hist, pivots);
    hipLaunchKernelGGL(compact_kernel, dim3(NB * BPP), dim3(256), 0, stream,
                       cls, pivots, cand_cnt, cand);
    hipLaunchKernelGGL(select_kernel, dim3(NPROB), dim3(512), 0, stream,
                       boxes, cand, cand_cnt, cand_idx, cand_score, boxdata, screen);
    hipLaunchKernelGGL(screen_kernel, dim3(NPROB * WAVES_PER_PROB / 4), dim3(256),
                       0, stream, screen, pair_cnt, pairs);
    hipLaunchKernelGGL(exact_kernel, dim3(256), dim3(256), 0, stream,
                       boxdata, pairs, pair_cnt, mask);
    hipLaunchKernelGGL(nms_out_kernel, dim3(NPROB), dim3(256), 0, stream,
                       boxes, cand_idx, cand_score, mask, out);
}

// Round 6
// 186.157 us; speedup vs baseline: 3.1044x; 1.2755x over previous
//
#include <hip/hip_runtime.h>
#include <cstdint>

#define NCLS 3
#define NPTS 100000
#define NB 2
#define PRE 512
#define POST 100
#define SCORE_TH 0.1f
#define NMS_TH 0.25
#define CAP 1024            // candidate buffer per problem (expect ~690)
#define BPP 98              // blocks per batch (98*1024 >= 100000)
#define NBINS 384           // fast-key bins: (key>>17) - (0xBD000000>>17)
#define BIN_SH 17
#define BIN_OFFW (0xBD000000u >> BIN_SH)
#define FMARG 2e-5f         // 2x bound on |f32 sigmoid - f64 sigmoid| (<=1e-6)
#define NPROB (NB * NCLS)
#define WAVES_PER_PROB 2304  // 36 upper-tri 64x64 cells x 64 rows

// ---------------- ws layout (bytes) ----------------
// [memset 0 region: 0 .. 205,888)
// hist      : uint32 [6*384]        @ 0          (9,216)
// cand_cnt  : uint32 [6] (pad 64)   @ 9,216
// mask      : uint64 [6*PRE*8]      @ 9,280      (196,608)
// [not memset]
// pivots    : uint32 [6] (pad 64)   @ 205,888
// cand      : uint64 [6*CAP]        @ 205,952    (49,152)
// cand_idx  : uint32 [6*PRE]        @ 255,104    (12,288)
// cand_scr  : float  [6*PRE]        @ 267,392    (12,288)
// boxdata   : double [6*PRE*20]     @ 279,680    (491,520)
// screen    : float  [6*PRE*8]      @ 771,200    (98,304)
// total ~0.87 MB

// boxdata per candidate (20 doubles):
// [0]=x [1]=y [2]=cos [3]=sin [4]=hx [5]=hy [6]=zlo [7]=zhi [8]=vol [9]=rad
// [10..13]=corner x (ref order) [14..17]=corner y
// screen per candidate (8 floats): [0]=x [1]=y [2]=zlo [3]=zhi [4]=rad

__device__ __forceinline__ uint32_t score_key(float x)
{
    // EXACT path: f64 sigmoid rounded to f32 == reference (absmax 0.0 R1-R5)
    double sd = 1.0 / (1.0 + exp(-(double)x));
    float s = (float)sd;
    if (!(s >= SCORE_TH)) s = -1.0f;
    uint32_t u = __float_as_uint(s);
    return (u & 0x80000000u) ? ~u : (u | 0x80000000u);
}

__device__ __forceinline__ float fast_sig(float x)
{
    return 1.0f / (1.0f + __expf(-x));
}

// monotone bin of a (possibly margin-adjusted) f32 score
__device__ __forceinline__ int fast_bin(float s)
{
    float v = (s >= SCORE_TH) ? s : -1.0f;
    uint32_t u = __float_as_uint(v);
    uint32_t kk = (u & 0x80000000u) ? ~u : (u | 0x80000000u);
    int b = (int)(kk >> BIN_SH) - (int)BIN_OFFW;
    return b < 0 ? 0 : (b > NBINS - 1 ? NBINS - 1 : b);
}

__global__ __launch_bounds__(256) void hist_kernel(
    const float* __restrict__ cls, uint32_t* __restrict__ hist)
{
    __shared__ uint32_t lh[NCLS * NBINS];
    for (int t = threadIdx.x; t < NCLS * NBINS; t += 256) lh[t] = 0;
    __syncthreads();
    const int b = blockIdx.x / BPP, cb = blockIdx.x % BPP;
    const int base = cb * 1024;
    for (int t = threadIdx.x; t < 1024; t += 256) {
        int i = base + t;
        if (i >= NPTS) continue;
        const float* cp = cls + ((size_t)b * NPTS + i) * NCLS;
        #pragma unroll
        for (int k = 0; k < NCLS; ++k)
            atomicAdd(&lh[k * NBINS + fast_bin(fast_sig(cp[k]))], 1u);
    }
    __syncthreads();
    for (int t = threadIdx.x; t < NCLS * NBINS; t += 256) {
        uint32_t c = lh[t];
        if (c)
            atomicAdd(&hist[(b * NCLS + t / NBINS) * NBINS + t % NBINS], c);
    }
}

__global__ __launch_bounds__(256) void pivot_kernel(
    const uint32_t* __restrict__ hist, uint32_t* __restrict__ pivots)
{
    const int p = blockIdx.x;
    const int tid = threadIdx.x;
    const uint32_t* H = hist + p * NBINS;
    __shared__ uint32_t csum[128];          // 3 bins per chunk
    if (tid < 128) {
        uint32_t s = 0;
        #pragma unroll
        for (int b = 0; b < 3; ++b) s += H[tid * 3 + b];
        csum[tid] = s;
    }
    __syncthreads();
    if (tid == 0) {
        int cum = 0, cchunk = 0;
        for (int c = 127; c >= 0; --c) {
            if (cum + (int)csum[c] >= PRE) { cchunk = c; break; }
            cum += (int)csum[c];
        }
        uint32_t pb = 0;
        for (int bin = cchunk * 3 + 2; bin >= cchunk * 3; --bin) {
            int h = (int)H[bin];
            if (cum + h >= PRE) { pb = (uint32_t)bin; break; }
            cum += h;
        }
        pivots[p] = pb;
    }
}

// Filter by fast bin with +FMARG slack (provable superset of exact top-512);
// exact f64 key computed only for the ~700/problem survivors.
__global__ __launch_bounds__(256) void compact_kernel(
    const float* __restrict__ cls, const uint32_t* __restrict__ pivots,
    uint32_t* __restrict__ cand_cnt, unsigned long long* __restrict__ cand)
{
    const int b = blockIdx.x / BPP, cb = blockIdx.x % BPP;
    const int base = cb * 1024;
    uint32_t pb[NCLS];
    #pragma unroll
    for (int k = 0; k < NCLS; ++k) pb[k] = pivots[b * NCLS + k];
    for (int t = threadIdx.x; t < 1024; t += 256) {
        int i = base + t;
        if (i >= NPTS) continue;
        const float* cp = cls + ((size_t)b * NPTS + i) * NCLS;
        #pragma unroll
        for (int k = 0; k < NCLS; ++k) {
            float sf = fast_sig(cp[k]);
            if ((uint32_t)fast_bin(sf + FMARG) >= pb[k]) {
                uint32_t kk = score_key(cp[k]);     // exact key
                int p = b * NCLS + k;
                unsigned int slot = atomicAdd(&cand_cnt[p], 1u);
                if (slot < CAP)
                    cand[(size_t)p * CAP + slot] =
                        ((unsigned long long)kk << 32) | (uint32_t)(~(uint32_t)i);
            }
        }
    }
}

__global__ __launch_bounds__(512) void select_kernel(
    const float* __restrict__ boxes, const unsigned long long* __restrict__ cand,
    const uint32_t* __restrict__ cand_cnt, uint32_t* __restrict__ cand_idx,
    float* __restrict__ cand_score, double* __restrict__ boxdata,
    float* __restrict__ screen)
{
    const int p = blockIdx.x;
    const int b = p / NCLS;
    const int tid = threadIdx.x;
    __shared__ unsigned long long skey[CAP];
    const int cnt = min((int)cand_cnt[p], CAP);
    for (int i = tid; i < CAP; i += 512)
        skey[i] = (i < cnt) ? cand[(size_t)p * CAP + i] : 0ull;
    __syncthreads();

    // bitonic sort, overall descending (all keys distinct; 0-padding sinks)
    for (int k2 = 2; k2 <= CAP; k2 <<= 1)
        for (int j = k2 >> 1; j > 0; j >>= 1) {
            for (int i = tid; i < CAP; i += 512) {
                int ixj = i ^ j;
                if (ixj > i) {
                    unsigned long long a = skey[i], c = skey[ixj];
                    bool up = ((i & k2) == 0);
                    if (up ? (a < c) : (a > c)) { skey[i] = c; skey[ixj] = a; }
                }
            }
            __syncthreads();
        }

    // epilogue: top-512 decode + f64 geometry + f32 screen
    if (tid >= PRE) return;
    unsigned long long key = skey[tid];
    double* D = boxdata + (size_t)(p * PRE + tid) * 20;
    float* S = screen + (size_t)(p * PRE + tid) * 8;
    if (key == 0ull) {                     // defensive: can't happen normally
        cand_idx[p * PRE + tid] = 0;
        cand_score[p * PRE + tid] = -1.0f;
        #pragma unroll
        for (int m = 0; m < 20; ++m) D[m] = 0.0;
        #pragma unroll
        for (int m = 0; m < 8; ++m) S[m] = 0.0f;
        return;
    }
    uint32_t idx = ~((uint32_t)key);
    uint32_t ov = (uint32_t)(key >> 32);
    uint32_t ub = (ov & 0x80000000u) ? (ov ^ 0x80000000u) : ~ov;
    float sc = __uint_as_float(ub);
    cand_idx[p * PRE + tid] = idx;
    cand_score[p * PRE + tid] = sc;

    const float* bp = boxes + ((size_t)b * NPTS + idx) * 7;
    double x = bp[0], y = bp[1], z = bp[2];
    double dx = bp[3], dy = bp[4], dz = bp[5], r = bp[6];
    double c = cos(r), s = sin(r);
    double hx = 0.5 * dx, hy = 0.5 * dy;
    double zlo = z - 0.5 * dz, zhi = z + 0.5 * dz;
    double rad = sqrt(hx * hx + hy * hy);
    D[0] = x; D[1] = y; D[2] = c; D[3] = s; D[4] = hx; D[5] = hy;
    D[6] = zlo; D[7] = zhi; D[8] = dx * dy * dz; D[9] = rad;
    const double lxs[4] = { hx, -hx, -hx,  hx };
    const double lys[4] = { hy,  hy, -hy, -hy };
    #pragma unroll
    for (int m = 0; m < 4; ++m) {
        D[10 + m] = x + lxs[m] * c - lys[m] * s;
        D[14 + m] = y + lxs[m] * s + lys[m] * c;
    }
    S[0] = (float)x; S[1] = (float)y; S[2] = (float)zlo; S[3] = (float)zhi;
    S[4] = (float)rad; S[5] = 0.0f; S[6] = 0.0f; S[7] = 0.0f;
}

// Fused screen + exact IoU. One wave per (prob, 64x64 cell, row): the wave
// owns mask word (prob,i,wj) EXCLUSIVELY, so the result is a single plain
// store — no atomics at all (R5's screen spent 54us on one global counter
// ping-ponging across XCD L2s). Survivors of the f32 screen (ballot) are
// processed in-wave with the verified wave-parallel f64 polygon clip.
__global__ __launch_bounds__(256) void iou_fused_kernel(
    const float* __restrict__ screen, const double* __restrict__ boxdata,
    unsigned long long* __restrict__ mask)
{
    const int W = blockIdx.x * 4 + (threadIdx.x >> 6);
    const int lane = threadIdx.x & 63;
    const int prob = W / WAVES_PER_PROB;
    int t = W - prob * WAVES_PER_PROB;
    int cell = t >> 6, r = t & 63;
    int wi = 0;
    while (cell >= 8 - wi) { cell -= 8 - wi; ++wi; }
    const int wj = wi + cell;
    const int bi = wi * 64 + r;
    const int j = wj * 64 + lane;

    // f32 screen (slack-safe): identical condition to R5's screen_kernel
    bool surv = false;
    {
        const float* SA = screen + (size_t)(prob * PRE + bi) * 8; // wave-uniform
        const float* SB = screen + (size_t)(prob * PRE + j) * 8;
        if (j > bi) {
            float4 a4 = *(const float4*)SA;           // x,y,zlo,zhi
            float4 b4 = *(const float4*)SB;
            float hz = fminf(a4.w, b4.w) - fmaxf(a4.z, b4.z);
            if (hz > 0.0f) {
                float ddx = a4.x - b4.x, ddy = a4.y - b4.y;
                float rs = SA[4] + SB[4] + 0.01f;
                surv = (ddx * ddx + ddy * ddy <= rs * rs);
            }
        }
    }
    unsigned long long sm = __ballot(surv);   // wave-uniform survivor set
    if (sm == 0ull) return;

    const double* A = boxdata + (size_t)(prob * PRE + bi) * 20;
    unsigned long long supw = 0ull;

    while (sm) {
        int jb = __ffsll(sm) - 1;
        sm &= sm - 1ull;
        const int bj = wj * 64 + jb;
        const double* B = boxdata + (size_t)(prob * PRE + bj) * 20;

        // lane owns one candidate point: 0-3 A-corners, 4-7 B-corners,
        // 8-23 edge intersections (reference construction order)
        double PX = 0.0, PY = 0.0;
        bool valid = false;
        if (lane < 8) {
            const double* S = (lane < 4) ? A : B;
            const double* O = (lane < 4) ? B : A;
            int m = lane & 3;
            PX = S[10 + m]; PY = S[14 + m];
            double rx = PX - O[0], ry = PY - O[1];
            double u =  rx * O[2] + ry * O[3];
            double v = -rx * O[3] + ry * O[2];
            valid = (fabs(u) <= O[4] + 1e-5) && (fabs(v) <= O[5] + 1e-5);
        } else if (lane < 24) {
            int e = lane - 8, m = e >> 2, nn = e & 3;
            double ax = A[10 + m], ay = A[14 + m];
            double rax = A[10 + ((m + 1) & 3)] - ax;
            double ray = A[14 + ((m + 1) & 3)] - ay;
            double bx = B[10 + nn], by = B[14 + nn];
            double rbx = B[10 + ((nn + 1) & 3)] - bx;
            double rby = B[14 + ((nn + 1) & 3)] - by;
            double d = rax * rby - ray * rbx;
            if (fabs(d) > 1e-8) {
                double qx = bx - ax, qy = by - ay;
                double tt = (qx * rby - qy * rbx) / d;
                double uu = (qx * ray - qy * rax) / d;
                valid = (tt >= 0.0 && tt <= 1.0 && uu >= 0.0 && uu <= 1.0);
                PX = ax + tt * rax; PY = ay + tt * ray;
            }
        }
        if (!valid) { PX = 0.0; PY = 0.0; }

        unsigned long long bal = __ballot(valid);
        int cnt = __popcll(bal);
        double sx = PX, sy = PY;          // invalid lanes contribute 0
        #pragma unroll
        for (int off = 32; off; off >>= 1) {
            sx += __shfl_xor(sx, off);
            sy += __shfl_xor(sy, off);
        }
        int cdiv = cnt > 0 ? cnt : 1;     // ref: / max(cnt, 1)
        double cxc = sx / cdiv, cyc = sy / cdiv;

        double ang = valid ? atan2(PY - cyc, PX - cxc) : 1e9;
        int sidx = lane;                  // construction order == ref slots

        // 64-lane bitonic sort asc by (ang, sidx) == numpy stable argsort
        #pragma unroll
        for (int k = 2; k <= 64; k <<= 1) {
            #pragma unroll
            for (int jj = k >> 1; jj > 0; jj >>= 1) {
                double oang = __shfl_xor(ang, jj);
                double opx  = __shfl_xor(PX, jj);
                double opy  = __shfl_xor(PY, jj);
                int    oidx = __shfl_xor(sidx, jj);
                bool iLow = (lane & jj) == 0;
                bool dirUp = (lane & k) == 0;
                bool mineFirst = (ang < oang) || (ang == oang && sidx < oidx);
                bool keepMine = (mineFirst == (iLow == dirUp));
                if (!keepMine) { ang = oang; PX = opx; PY = opy; sidx = oidx; }
            }
        }

        // centered shoelace over sorted lanes [0, cnt)
        double nxp = __shfl(PX, (lane + 1) & 63);
        double nyp = __shfl(PY, (lane + 1) & 63);
        double fx  = __shfl(PX, 0);
        double fy  = __shfl(PY, 0);
        bool last = (lane == cnt - 1);
        double qx = last ? fx : nxp, qy = last ? fy : nyp;
        double contrib = 0.0;
        if (lane < cnt)
            contrib = (PX - cxc) * (qy - cyc) - (PY - cyc) * (qx - cxc);
        #pragma unroll
        for (int off = 32; off; off >>= 1) contrib += __shfl_xor(contrib, off);
        double inter = (cnt >= 3) ? 0.5 * fabs(contrib) : 0.0;

        // all lanes compute sup identically (contrib sum is wave-uniform)
        double zt = fmin(A[7], B[7]);
        double zb = fmax(A[6], B[6]);
        double hz = zt - zb;
        bool sup = false;
        if (hz > 0.0) {
            double i3 = inter * hz;
            double den = A[8] + B[8] - i3;
            if (den < 1e-8) den = 1e-8;
            sup = (i3 / den) > (double)NMS_TH;
        }
        if (sup) supw |= 1ull << jb;
    }

    if (lane == 0 && supw)
        mask[(size_t)(prob * PRE + bi) * 8 + wj] = supw;   // exclusive word
}

__global__ __launch_bounds__(256) void nms_out_kernel(
    const float* __restrict__ boxes, const uint32_t* __restrict__ cand_idx,
    const float* __restrict__ cand_score,
    const unsigned long long* __restrict__ mask, float* __restrict__ out)
{
    const int p = blockIdx.x;
    const int b = p / NCLS, k = p % NCLS;
    const int tid = threadIdx.x;

    __shared__ unsigned long long smask[PRE * 8];   // 32 KB
    __shared__ float sscore[PRE];
    __shared__ int slist[POST];
    __shared__ int scnt;

    for (int w = tid; w < PRE * 8; w += 256)
        smask[w] = mask[(size_t)p * PRE * 8 + w];
    for (int i = tid; i < PRE; i += 256)
        sscore[i] = cand_score[p * PRE + i];
    __syncthreads();

    // Wave-parallel greedy scan; early break at c==POST (later kept rows
    // can never reach the POST-capped output).
    if (tid < 64) {
        const int lane = tid;
        uint32_t supbits = 0;
        int c = 0;
        for (int i = 0; i < PRE; ++i) {
            uint32_t sb = (uint32_t)__shfl((int)supbits, i & 63);
            bool sup_i = (sb >> (i >> 6)) & 1u;
            float sc = sscore[i];                      // LDS broadcast
            bool keep = (sc >= SCORE_TH) && !sup_i;    // wave-uniform
            if (keep) {
                if (lane == 0) slist[c] = i;
                ++c;
                if (c >= POST) break;
                #pragma unroll
                for (int w = 0; w < 8; ++w) {
                    unsigned long long m = smask[i * 8 + w];  // broadcast
                    supbits |= (uint32_t)((m >> lane) & 1ull) << w;
                }
            }
        }
        if (lane == 0) scnt = c;
    }
    __syncthreads();

    const int cnt = scnt;
    for (int t = tid; t < POST; t += 256) {
        int row = b * (NCLS * POST) + k * POST + t;          // 0..599
        float* ob = out + (size_t)row * 7;
        float* os = out + (size_t)NB * NCLS * POST * 7 + row;
        float* ol = out + (size_t)NB * NCLS * POST * 7 + (size_t)NB * NCLS * POST + row;
        if (t < cnt) {
            int r = slist[t];
            uint32_t idx = cand_idx[p * PRE + r];
            const float* bp = boxes + ((size_t)b * NPTS + idx) * 7;
            #pragma unroll
            for (int c7 = 0; c7 < 7; ++c7) ob[c7] = bp[c7];
            *os = sscore[r];
            *ol = (float)(k + 1);
        } else {
            #pragma unroll
            for (int c7 = 0; c7 < 7; ++c7) ob[c7] = 0.0f;
            *os = 0.0f;
            *ol = 0.0f;
        }
    }
}

extern "C" void kernel_launch(void* const* d_in, const int* in_sizes, int n_in,
                              void* d_out, int out_size, void* d_ws, size_t ws_size,
                              hipStream_t stream)
{
    (void)in_sizes; (void)n_in; (void)out_size; (void)ws_size;
    const float* cls   = (const float*)d_in[0];   // (2,100000,3) f32
    const float* boxes = (const float*)d_in[1];   // (2,100000,7) f32
    float* out = (float*)d_out;

    char* ws = (char*)d_ws;
    uint32_t* hist        = (uint32_t*)(ws);
    uint32_t* cand_cnt    = (uint32_t*)(ws + 9216);
    unsigned long long* mask = (unsigned long long*)(ws + 9280);
    uint32_t* pivots      = (uint32_t*)(ws + 205888);
    unsigned long long* cand = (unsigned long long*)(ws + 205952);
    uint32_t* cand_idx    = (uint32_t*)(ws + 255104);
    float*    cand_score  = (float*)   (ws + 267392);
    double*   boxdata     = (double*)  (ws + 279680);
    float*    screen      = (float*)   (ws + 771200);

    // zero hist + cand_cnt + mask (ws poisoned 0xAA each call)
    hipMemsetAsync(ws, 0, 205888, stream);

    hipLaunchKernelGGL(hist_kernel, dim3(NB * BPP), dim3(256), 0, stream,
                       cls, hist);
    hipLaunchKernelGGL(pivot_kernel, dim3(NPROB), dim3(256), 0, stream,
                       hist, pivots);
    hipLaunchKernelGGL(compact_kernel, dim3(NB * BPP), dim3(256), 0, stream,
                       cls, pivots, cand_cnt, cand);
    hipLaunchKernelGGL(select_kernel, dim3(NPROB), dim3(512), 0, stream,
                       boxes, cand, cand_cnt, cand_idx, cand_score, boxdata, screen);
    hipLaunchKernelGGL(iou_fused_kernel, dim3(NPROB * WAVES_PER_PROB / 4),
                       dim3(256), 0, stream, screen, boxdata, mask);
    hipLaunchKernelGGL(nms_out_kernel, dim3(NPROB), dim3(256), 0, stream,
                       boxes, cand_idx, cand_score, mask, out);
}

// Round 7
// 147.380 us; speedup vs baseline: 3.9212x; 1.2631x over previous
//
#include <hip/hip_runtime.h>
#include <cstdint>

#define NCLS 3
#define NPTS 100000
#define NB 2
#define PRE 512
#define POST 100
#define SCORE_TH 0.1f
#define NMS_TH 0.25
#define CAP 1024            // candidate buffer per problem (expect ~690)
#define BPP 98              // 1024-point chunks per plane (98*1024 >= 100000)
#define NBINS 384           // fast-key bins: (key>>17) - (0xBD000000>>17)
#define BIN_SH 17
#define BIN_OFFW (0xBD000000u >> BIN_SH)
#define FMARG 2e-5f         // 2x bound on |f32 sigmoid - f64 sigmoid| (<=1e-6)
#define NPROB (NB * NCLS)
#define WAVES_PER_PROB 2304  // 36 upper-tri 64x64 cells x 64 rows

// ---------------- ws layout (bytes) ----------------
// [memset 0 region: 0 .. 205,888)
// hist      : uint32 [6*384]        @ 0          (9,216)
// cand_cnt  : uint32 [6] (pad 64)   @ 9,216
// mask      : uint64 [6*PRE*8]      @ 9,280      (196,608)
// [not memset]
// pivots    : uint32 [6] (pad 64)   @ 205,888
// cand      : uint64 [6*CAP]        @ 205,952    (49,152)
// cand_idx  : uint32 [6*PRE]        @ 255,104    (12,288)
// cand_scr  : float  [6*PRE]        @ 267,392    (12,288)
// boxdata   : double [6*PRE*20]     @ 279,680    (491,520)
// screen    : float  [6*PRE*8]      @ 771,200    (98,304)
// sf        : float  [6*NPTS]       @ 869,504    (2,400,000)  plane-major
// total ~3.27 MB

__device__ __forceinline__ uint32_t score_key(float x)
{
    // EXACT path: f64 sigmoid rounded to f32 == reference (absmax 0.0 R1-R6)
    double sd = 1.0 / (1.0 + exp(-(double)x));
    float s = (float)sd;
    if (!(s >= SCORE_TH)) s = -1.0f;
    uint32_t u = __float_as_uint(s);
    return (u & 0x80000000u) ? ~u : (u | 0x80000000u);
}

__device__ __forceinline__ float fast_sig(float x)
{
    return 1.0f / (1.0f + __expf(-x));
}

// monotone bin of a (possibly margin-adjusted) f32 score
__device__ __forceinline__ int fast_bin(float s)
{
    float v = (s >= SCORE_TH) ? s : -1.0f;
    uint32_t u = __float_as_uint(v);
    uint32_t kk = (u & 0x80000000u) ? ~u : (u | 0x80000000u);
    int b = (int)(kk >> BIN_SH) - (int)BIN_OFFW;
    return b < 0 ? 0 : (b > NBINS - 1 ? NBINS - 1 : b);
}

// 1024-thread blocks: R6's 256-thread version ran 784 waves chip-wide and
// was latency-bound (VALUBusy 1.6%). Also stores fast_sig per element so
// compact never recomputes it.
__global__ __launch_bounds__(1024) void hist_kernel(
    const float* __restrict__ cls, float* __restrict__ sf,
    uint32_t* __restrict__ hist)
{
    __shared__ uint32_t lh[NCLS * NBINS];
    for (int t = threadIdx.x; t < NCLS * NBINS; t += 1024) lh[t] = 0;
    __syncthreads();
    const int b = blockIdx.x / BPP, cb = blockIdx.x % BPP;
    const int i = cb * 1024 + threadIdx.x;
    if (i < NPTS) {
        const float* cp = cls + ((size_t)b * NPTS + i) * NCLS;
        #pragma unroll
        for (int k = 0; k < NCLS; ++k) {
            float sfv = fast_sig(cp[k]);
            sf[(size_t)(b * NCLS + k) * NPTS + i] = sfv;
            atomicAdd(&lh[k * NBINS + fast_bin(sfv)], 1u);
        }
    }
    __syncthreads();
    for (int t = threadIdx.x; t < NCLS * NBINS; t += 1024) {
        uint32_t c = lh[t];
        if (c)
            atomicAdd(&hist[(b * NCLS + t / NBINS) * NBINS + t % NBINS], c);
    }
}

__global__ __launch_bounds__(256) void pivot_kernel(
    const uint32_t* __restrict__ hist, uint32_t* __restrict__ pivots)
{
    const int p = blockIdx.x;
    const int tid = threadIdx.x;
    const uint32_t* H = hist + p * NBINS;
    __shared__ uint32_t csum[128];          // 3 bins per chunk
    if (tid < 128) {
        uint32_t s = 0;
        #pragma unroll
        for (int b = 0; b < 3; ++b) s += H[tid * 3 + b];
        csum[tid] = s;
    }
    __syncthreads();
    if (tid == 0) {
        int cum = 0, cchunk = 0;
        for (int c = 127; c >= 0; --c) {
            if (cum + (int)csum[c] >= PRE) { cchunk = c; break; }
            cum += (int)csum[c];
        }
        uint32_t pb = 0;
        for (int bin = cchunk * 3 + 2; bin >= cchunk * 3; --bin) {
            int h = (int)H[bin];
            if (cum + h >= PRE) { pb = (uint32_t)bin; break; }
            cum += h;
        }
        pivots[p] = pb;
    }
}

// One block = one 1024-element segment of one problem plane. Each thread
// contributes <=1 survivor -> LDS stage never overflows; ONE global
// atomicAdd per block (588 total, was ~4.2k on 6 hot addresses in R6).
__global__ __launch_bounds__(1024) void compact_kernel(
    const float* __restrict__ cls, const float* __restrict__ sf,
    const uint32_t* __restrict__ pivots, uint32_t* __restrict__ cand_cnt,
    unsigned long long* __restrict__ cand)
{
    __shared__ unsigned long long stage[1024];
    __shared__ uint32_t lcnt, lbase;
    if (threadIdx.x == 0) lcnt = 0;
    __syncthreads();

    const int p = blockIdx.x / BPP, cb = blockIdx.x % BPP;
    const int i = cb * 1024 + threadIdx.x;
    const uint32_t pb = pivots[p];

    bool sv = false;
    unsigned long long entry = 0;
    if (i < NPTS) {
        float sfv = sf[(size_t)p * NPTS + i];      // identical bits to R6's
        if ((uint32_t)fast_bin(sfv + FMARG) >= pb) {
            const int b = p / NCLS, k = p % NCLS;
            uint32_t kk = score_key(cls[((size_t)b * NPTS + i) * NCLS + k]);
            entry = ((unsigned long long)kk << 32) | (uint32_t)(~(uint32_t)i);
            sv = true;
        }
    }
    if (sv) {
        uint32_t slot = atomicAdd(&lcnt, 1u);      // < 1024 by construction
        stage[slot] = entry;
    }
    __syncthreads();
    if (threadIdx.x == 0 && lcnt)
        lbase = atomicAdd(&cand_cnt[p], lcnt);
    __syncthreads();
    const uint32_t n = lcnt;
    if (n) {
        const uint32_t base = lbase;
        for (uint32_t e = threadIdx.x; e < n; e += 1024) {
            uint32_t g = base + e;
            if (g < CAP) cand[(size_t)p * CAP + g] = stage[e];
        }
    }
}

__global__ __launch_bounds__(1024) void select_kernel(
    const float* __restrict__ boxes, const unsigned long long* __restrict__ cand,
    const uint32_t* __restrict__ cand_cnt, uint32_t* __restrict__ cand_idx,
    float* __restrict__ cand_score, double* __restrict__ boxdata,
    float* __restrict__ screen)
{
    const int p = blockIdx.x;
    const int b = p / NCLS;
    const int tid = threadIdx.x;
    __shared__ unsigned long long skey[CAP];
    const int cnt = min((int)cand_cnt[p], CAP);
    skey[tid] = (tid < cnt) ? cand[(size_t)p * CAP + tid] : 0ull;
    __syncthreads();

    // bitonic sort, one slot per thread, overall descending
    for (int k2 = 2; k2 <= CAP; k2 <<= 1)
        for (int j = k2 >> 1; j > 0; j >>= 1) {
            int ixj = tid ^ j;
            if (ixj > tid) {
                unsigned long long a = skey[tid], c = skey[ixj];
                bool up = ((tid & k2) == 0);
                if (up ? (a < c) : (a > c)) { skey[tid] = c; skey[ixj] = a; }
            }
            __syncthreads();
        }

    // epilogue: top-512 decode + f64 geometry + f32 screen
    if (tid >= PRE) return;
    unsigned long long key = skey[tid];
    double* D = boxdata + (size_t)(p * PRE + tid) * 20;
    float* S = screen + (size_t)(p * PRE + tid) * 8;
    if (key == 0ull) {                     // defensive: can't happen normally
        cand_idx[p * PRE + tid] = 0;
        cand_score[p * PRE + tid] = -1.0f;
        #pragma unroll
        for (int m = 0; m < 20; ++m) D[m] = 0.0;
        #pragma unroll
        for (int m = 0; m < 8; ++m) S[m] = 0.0f;
        return;
    }
    uint32_t idx = ~((uint32_t)key);
    uint32_t ov = (uint32_t)(key >> 32);
    uint32_t ub = (ov & 0x80000000u) ? (ov ^ 0x80000000u) : ~ov;
    float sc = __uint_as_float(ub);
    cand_idx[p * PRE + tid] = idx;
    cand_score[p * PRE + tid] = sc;

    const float* bp = boxes + ((size_t)b * NPTS + idx) * 7;
    double x = bp[0], y = bp[1], z = bp[2];
    double dx = bp[3], dy = bp[4], dz = bp[5], r = bp[6];
    double c = cos(r), s = sin(r);
    double hx = 0.5 * dx, hy = 0.5 * dy;
    double zlo = z - 0.5 * dz, zhi = z + 0.5 * dz;
    double rad = sqrt(hx * hx + hy * hy);
    D[0] = x; D[1] = y; D[2] = c; D[3] = s; D[4] = hx; D[5] = hy;
    D[6] = zlo; D[7] = zhi; D[8] = dx * dy * dz; D[9] = rad;
    const double lxs[4] = { hx, -hx, -hx,  hx };
    const double lys[4] = { hy,  hy, -hy, -hy };
    #pragma unroll
    for (int m = 0; m < 4; ++m) {
        D[10 + m] = x + lxs[m] * c - lys[m] * s;
        D[14 + m] = y + lxs[m] * s + lys[m] * c;
    }
    S[0] = (float)x; S[1] = (float)y; S[2] = (float)zlo; S[3] = (float)zhi;
    S[4] = (float)rad; S[5] = 0.0f; S[6] = 0.0f; S[7] = 0.0f;
}

// Fused screen + exact IoU. One wave per (prob, cell, row): wave owns mask
// word (prob,i,wj) exclusively -> single plain store, zero atomics.
__global__ __launch_bounds__(256) void iou_fused_kernel(
    const float* __restrict__ screen, const double* __restrict__ boxdata,
    unsigned long long* __restrict__ mask)
{
    const int W = blockIdx.x * 4 + (threadIdx.x >> 6);
    const int lane = threadIdx.x & 63;
    const int prob = W / WAVES_PER_PROB;
    int t = W - prob * WAVES_PER_PROB;
    int cell = t >> 6, r = t & 63;
    int wi = 0;
    while (cell >= 8 - wi) { cell -= 8 - wi; ++wi; }
    const int wj = wi + cell;
    const int bi = wi * 64 + r;
    const int j = wj * 64 + lane;

    bool surv = false;
    {
        const float* SA = screen + (size_t)(prob * PRE + bi) * 8; // wave-uniform
        const float* SB = screen + (size_t)(prob * PRE + j) * 8;
        if (j > bi) {
            float4 a4 = *(const float4*)SA;           // x,y,zlo,zhi
            float4 b4 = *(const float4*)SB;
            float hz = fminf(a4.w, b4.w) - fmaxf(a4.z, b4.z);
            if (hz > 0.0f) {
                float ddx = a4.x - b4.x, ddy = a4.y - b4.y;
                float rs = SA[4] + SB[4] + 0.01f;
                surv = (ddx * ddx + ddy * ddy <= rs * rs);
            }
        }
    }
    unsigned long long sm = __ballot(surv);   // wave-uniform survivor set
    if (sm == 0ull) return;

    const double* A = boxdata + (size_t)(prob * PRE + bi) * 20;
    unsigned long long supw = 0ull;

    while (sm) {
        int jb = __ffsll(sm) - 1;
        sm &= sm - 1ull;
        const int bj = wj * 64 + jb;
        const double* B = boxdata + (size_t)(prob * PRE + bj) * 20;

        // lane owns one candidate point: 0-3 A-corners, 4-7 B-corners,
        // 8-23 edge intersections (reference construction order)
        double PX = 0.0, PY = 0.0;
        bool valid = false;
        if (lane < 8) {
            const double* S = (lane < 4) ? A : B;
            const double* O = (lane < 4) ? B : A;
            int m = lane & 3;
            PX = S[10 + m]; PY = S[14 + m];
            double rx = PX - O[0], ry = PY - O[1];
            double u =  rx * O[2] + ry * O[3];
            double v = -rx * O[3] + ry * O[2];
            valid = (fabs(u) <= O[4] + 1e-5) && (fabs(v) <= O[5] + 1e-5);
        } else if (lane < 24) {
            int e = lane - 8, m = e >> 2, nn = e & 3;
            double ax = A[10 + m], ay = A[14 + m];
            double rax = A[10 + ((m + 1) & 3)] - ax;
            double ray = A[14 + ((m + 1) & 3)] - ay;
            double bx = B[10 + nn], by = B[14 + nn];
            double rbx = B[10 + ((nn + 1) & 3)] - bx;
            double rby = B[14 + ((nn + 1) & 3)] - by;
            double d = rax * rby - ray * rbx;
            if (fabs(d) > 1e-8) {
                double qx = bx - ax, qy = by - ay;
                double tt = (qx * rby - qy * rbx) / d;
                double uu = (qx * ray - qy * rax) / d;
                valid = (tt >= 0.0 && tt <= 1.0 && uu >= 0.0 && uu <= 1.0);
                PX = ax + tt * rax; PY = ay + tt * ray;
            }
        }
        if (!valid) { PX = 0.0; PY = 0.0; }

        unsigned long long bal = __ballot(valid);
        int cnt = __popcll(bal);
        double sx = PX, sy = PY;          // invalid lanes contribute 0
        #pragma unroll
        for (int off = 32; off; off >>= 1) {
            sx += __shfl_xor(sx, off);
            sy += __shfl_xor(sy, off);
        }
        int cdiv = cnt > 0 ? cnt : 1;     // ref: / max(cnt, 1)
        double cxc = sx / cdiv, cyc = sy / cdiv;

        double ang = valid ? atan2(PY - cyc, PX - cxc) : 1e9;
        int sidx = lane;                  // construction order == ref slots

        // 64-lane bitonic sort asc by (ang, sidx) == numpy stable argsort
        #pragma unroll
        for (int k = 2; k <= 64; k <<= 1) {
            #pragma unroll
            for (int jj = k >> 1; jj > 0; jj >>= 1) {
                double oang = __shfl_xor(ang, jj);
                double opx  = __shfl_xor(PX, jj);
                double opy  = __shfl_xor(PY, jj);
                int    oidx = __shfl_xor(sidx, jj);
                bool iLow = (lane & jj) == 0;
                bool dirUp = (lane & k) == 0;
                bool mineFirst = (ang < oang) || (ang == oang && sidx < oidx);
                bool keepMine = (mineFirst == (iLow == dirUp));
                if (!keepMine) { ang = oang; PX = opx; PY = opy; sidx = oidx; }
            }
        }

        // centered shoelace over sorted lanes [0, cnt)
        double nxp = __shfl(PX, (lane + 1) & 63);
        double nyp = __shfl(PY, (lane + 1) & 63);
        double fx  = __shfl(PX, 0);
        double fy  = __shfl(PY, 0);
        bool last = (lane == cnt - 1);
        double qx = last ? fx : nxp, qy = last ? fy : nyp;
        double contrib = 0.0;
        if (lane < cnt)
            contrib = (PX - cxc) * (qy - cyc) - (PY - cyc) * (qx - cxc);
        #pragma unroll
        for (int off = 32; off; off >>= 1) contrib += __shfl_xor(contrib, off);
        double inter = (cnt >= 3) ? 0.5 * fabs(contrib) : 0.0;

        double zt = fmin(A[7], B[7]);
        double zb = fmax(A[6], B[6]);
        double hz = zt - zb;
        bool sup = false;
        if (hz > 0.0) {
            double i3 = inter * hz;
            double den = A[8] + B[8] - i3;
            if (den < 1e-8) den = 1e-8;
            sup = (i3 / den) > (double)NMS_TH;
        }
        if (sup) supw |= 1ull << jb;
    }

    if (lane == 0 && supw)
        mask[(size_t)(prob * PRE + bi) * 8 + wj] = supw;   // exclusive word
}

__global__ __launch_bounds__(256) void nms_out_kernel(
    const float* __restrict__ boxes, const uint32_t* __restrict__ cand_idx,
    const float* __restrict__ cand_score,
    const unsigned long long* __restrict__ mask, float* __restrict__ out)
{
    const int p = blockIdx.x;
    const int b = p / NCLS, k = p % NCLS;
    const int tid = threadIdx.x;

    __shared__ unsigned long long smask[PRE * 8];   // 32 KB
    __shared__ float sscore[PRE];
    __shared__ int slist[POST];
    __shared__ int scnt;

    for (int w = tid; w < PRE * 8; w += 256)
        smask[w] = mask[(size_t)p * PRE * 8 + w];
    for (int i = tid; i < PRE; i += 256)
        sscore[i] = cand_score[p * PRE + i];
    __syncthreads();

    // Wave-parallel greedy scan; early break at c==POST (later kept rows
    // can never reach the POST-capped output).
    if (tid < 64) {
        const int lane = tid;
        uint32_t supbits = 0;
        int c = 0;
        for (int i = 0; i < PRE; ++i) {
            uint32_t sb = (uint32_t)__shfl((int)supbits, i & 63);
            bool sup_i = (sb >> (i >> 6)) & 1u;
            float sc = sscore[i];                      // LDS broadcast
            bool keep = (sc >= SCORE_TH) && !sup_i;    // wave-uniform
            if (keep) {
                if (lane == 0) slist[c] = i;
                ++c;
                if (c >= POST) break;
                #pragma unroll
                for (int w = 0; w < 8; ++w) {
                    unsigned long long m = smask[i * 8 + w];  // broadcast
                    supbits |= (uint32_t)((m >> lane) & 1ull) << w;
                }
            }
        }
        if (lane == 0) scnt = c;
    }
    __syncthreads();

    const int cnt = scnt;
    for (int t = tid; t < POST; t += 256) {
        int row = b * (NCLS * POST) + k * POST + t;          // 0..599
        float* ob = out + (size_t)row * 7;
        float* os = out + (size_t)NB * NCLS * POST * 7 + row;
        float* ol = out + (size_t)NB * NCLS * POST * 7 + (size_t)NB * NCLS * POST + row;
        if (t < cnt) {
            int r = slist[t];
            uint32_t idx = cand_idx[p * PRE + r];
            const float* bp = boxes + ((size_t)b * NPTS + idx) * 7;
            #pragma unroll
            for (int c7 = 0; c7 < 7; ++c7) ob[c7] = bp[c7];
            *os = sscore[r];
            *ol = (float)(k + 1);
        } else {
            #pragma unroll
            for (int c7 = 0; c7 < 7; ++c7) ob[c7] = 0.0f;
            *os = 0.0f;
            *ol = 0.0f;
        }
    }
}

extern "C" void kernel_launch(void* const* d_in, const int* in_sizes, int n_in,
                              void* d_out, int out_size, void* d_ws, size_t ws_size,
                              hipStream_t stream)
{
    (void)in_sizes; (void)n_in; (void)out_size; (void)ws_size;
    const float* cls   = (const float*)d_in[0];   // (2,100000,3) f32
    const float* boxes = (const float*)d_in[1];   // (2,100000,7) f32
    float* out = (float*)d_out;

    char* ws = (char*)d_ws;
    uint32_t* hist        = (uint32_t*)(ws);
    uint32_t* cand_cnt    = (uint32_t*)(ws + 9216);
    unsigned long long* mask = (unsigned long long*)(ws + 9280);
    uint32_t* pivots      = (uint32_t*)(ws + 205888);
    unsigned long long* cand = (unsigned long long*)(ws + 205952);
    uint32_t* cand_idx    = (uint32_t*)(ws + 255104);
    float*    cand_score  = (float*)   (ws + 267392);
    double*   boxdata     = (double*)  (ws + 279680);
    float*    screen      = (float*)   (ws + 771200);
    float*    sf          = (float*)   (ws + 869504);

    // zero hist + cand_cnt + mask (ws poisoned 0xAA each call)
    hipMemsetAsync(ws, 0, 205888, stream);

    hipLaunchKernelGGL(hist_kernel, dim3(NB * BPP), dim3(1024), 0, stream,
                       cls, sf, hist);
    hipLaunchKernelGGL(pivot_kernel, dim3(NPROB), dim3(256), 0, stream,
                       hist, pivots);
    hipLaunchKernelGGL(compact_kernel, dim3(NPROB * BPP), dim3(1024), 0, stream,
                       cls, sf, pivots, cand_cnt, cand);
    hipLaunchKernelGGL(select_kernel, dim3(NPROB), dim3(1024), 0, stream,
                       boxes, cand, cand_cnt, cand_idx, cand_score, boxdata, screen);
    hipLaunchKernelGGL(iou_fused_kernel, dim3(NPROB * WAVES_PER_PROB / 4),
                       dim3(256), 0, stream, screen, boxdata, mask);
    hipLaunchKernelGGL(nms_out_kernel, dim3(NPROB), dim3(256), 0, stream,
                       boxes, cand_idx, cand_score, mask, out);
}

// Round 8
// 143.547 us; speedup vs baseline: 4.0259x; 1.0267x over previous
//
#include <hip/hip_runtime.h>
#include <cstdint>

#define NCLS 3
#define NPTS 100000
#define NB 2
#define PRE 512
#define POST 100
#define SCORE_TH 0.1f
#define NMS_TH 0.25
#define CAP 1024            // candidate buffer per problem (expect ~690)
#define BPP 98              // 1024-point chunks per plane (98*1024 >= 100000)
#define NBINS 384           // fast-key bins: (key>>17) - (0xBD000000>>17)
#define BIN_SH 17
#define BIN_OFFW (0xBD000000u >> BIN_SH)
#define FMARG 2e-5f         // 2x bound on |f32 sigmoid - f64 sigmoid| (<=1e-6)
#define NPROB (NB * NCLS)
#define WAVES_PER_PROB 2304  // 36 upper-tri 64x64 cells x 64 rows
#define HPB (NCLS * NBINS)   // 1152 partial-hist entries per hist block

// ---------------- ws layout (bytes) ---------------- (NO memset needed)
// pivots    : uint32 [6] (pad 64)   @ 0
// cand_cnt  : uint32 [6] (pad 64)   @ 64          (zeroed by pivot_kernel)
// mask      : uint64 [6*PRE*8]      @ 128         (196,608; upper-tri words
//                                                  always stored by iou_fused;
//                                                  lower-tri garbage harmless)
// cand      : uint64 [6*CAP]        @ 196,736     (49,152)
// cand_idx  : uint32 [6*PRE]        @ 245,888     (12,288)
// cand_scr  : float  [6*PRE]        @ 258,176     (12,288)
// boxdata   : double [6*PRE*20]     @ 270,464     (491,520)
// screen    : float  [6*PRE*8]      @ 761,984     (98,304)
// sf        : float  [6*NPTS]       @ 860,288     (2,400,000)  plane-major
// hist_part : uint32 [196*1152]     @ 3,260,288   (903,168)
// total ~4.16 MB

__device__ __forceinline__ uint32_t score_key(float x)
{
    // EXACT path: f64 sigmoid rounded to f32 == reference (absmax 0.0 R1-R7)
    double sd = 1.0 / (1.0 + exp(-(double)x));
    float s = (float)sd;
    if (!(s >= SCORE_TH)) s = -1.0f;
    uint32_t u = __float_as_uint(s);
    return (u & 0x80000000u) ? ~u : (u | 0x80000000u);
}

__device__ __forceinline__ float fast_sig(float x)
{
    return 1.0f / (1.0f + __expf(-x));
}

// monotone bin of a (possibly margin-adjusted) f32 score
__device__ __forceinline__ int fast_bin(float s)
{
    float v = (s >= SCORE_TH) ? s : -1.0f;
    uint32_t u = __float_as_uint(v);
    uint32_t kk = (u & 0x80000000u) ? ~u : (u | 0x80000000u);
    int b = (int)(kk >> BIN_SH) - (int)BIN_OFFW;
    return b < 0 ? 0 : (b > NBINS - 1 ? NBINS - 1 : b);
}

// Per-block partial histograms (plain stores -> no global pre-zero needed).
// Also stores fast_sig per element so compact never recomputes it.
__global__ __launch_bounds__(1024) void hist_kernel(
    const float* __restrict__ cls, float* __restrict__ sf,
    uint32_t* __restrict__ hist_part)
{
    __shared__ uint32_t lh[HPB];
    for (int t = threadIdx.x; t < HPB; t += 1024) lh[t] = 0;
    __syncthreads();
    const int b = blockIdx.x / BPP, cb = blockIdx.x % BPP;
    const int i = cb * 1024 + threadIdx.x;
    if (i < NPTS) {
        const float* cp = cls + ((size_t)b * NPTS + i) * NCLS;
        #pragma unroll
        for (int k = 0; k < NCLS; ++k) {
            float sfv = fast_sig(cp[k]);
            sf[(size_t)(b * NCLS + k) * NPTS + i] = sfv;
            atomicAdd(&lh[k * NBINS + fast_bin(sfv)], 1u);
        }
    }
    __syncthreads();
    uint32_t* P = hist_part + (size_t)blockIdx.x * HPB;
    for (int t = threadIdx.x; t < HPB; t += 1024) P[t] = lh[t];
}

// Reduce partials, find pivot bin, and zero cand_cnt for the next stage.
__global__ __launch_bounds__(512) void pivot_kernel(
    const uint32_t* __restrict__ hist_part, uint32_t* __restrict__ pivots,
    uint32_t* __restrict__ cand_cnt)
{
    const int p = blockIdx.x;              // b*3+k
    const int b = p / NCLS, k = p % NCLS;
    const int tid = threadIdx.x;
    __shared__ uint32_t bins[NBINS];
    __shared__ uint32_t csum[128];
    if (tid < NBINS) {
        uint32_t s = 0;
        const uint32_t* base = hist_part + (size_t)b * BPP * HPB + k * NBINS + tid;
        for (int cb = 0; cb < BPP; ++cb)
            s += base[(size_t)cb * HPB];
        bins[tid] = s;
    }
    __syncthreads();
    if (tid < 128)
        csum[tid] = bins[tid * 3] + bins[tid * 3 + 1] + bins[tid * 3 + 2];
    __syncthreads();
    if (tid == 0) {
        int cum = 0, cchunk = 0;
        for (int c = 127; c >= 0; --c) {
            if (cum + (int)csum[c] >= PRE) { cchunk = c; break; }
            cum += (int)csum[c];
        }
        uint32_t pb = 0;
        for (int bin = cchunk * 3 + 2; bin >= cchunk * 3; --bin) {
            int h = (int)bins[bin];
            if (cum + h >= PRE) { pb = (uint32_t)bin; break; }
            cum += h;
        }
        pivots[p] = pb;
        cand_cnt[p] = 0;                   // replaces the ws memset
    }
}

// One block = one 1024-element segment of one problem plane. Each thread
// contributes <=1 survivor -> LDS stage never overflows; ONE global
// atomicAdd per block (588 total, spread addresses).
__global__ __launch_bounds__(1024) void compact_kernel(
    const float* __restrict__ cls, const float* __restrict__ sf,
    const uint32_t* __restrict__ pivots, uint32_t* __restrict__ cand_cnt,
    unsigned long long* __restrict__ cand)
{
    __shared__ unsigned long long stage[1024];
    __shared__ uint32_t lcnt, lbase;
    if (threadIdx.x == 0) lcnt = 0;
    __syncthreads();

    const int p = blockIdx.x / BPP, cb = blockIdx.x % BPP;
    const int i = cb * 1024 + threadIdx.x;
    const uint32_t pb = pivots[p];

    bool sv = false;
    unsigned long long entry = 0;
    if (i < NPTS) {
        float sfv = sf[(size_t)p * NPTS + i];      // identical bits to hist's
        if ((uint32_t)fast_bin(sfv + FMARG) >= pb) {
            const int b = p / NCLS, k = p % NCLS;
            uint32_t kk = score_key(cls[((size_t)b * NPTS + i) * NCLS + k]);
            entry = ((unsigned long long)kk << 32) | (uint32_t)(~(uint32_t)i);
            sv = true;
        }
    }
    if (sv) {
        uint32_t slot = atomicAdd(&lcnt, 1u);      // < 1024 by construction
        stage[slot] = entry;
    }
    __syncthreads();
    if (threadIdx.x == 0 && lcnt)
        lbase = atomicAdd(&cand_cnt[p], lcnt);
    __syncthreads();
    const uint32_t n = lcnt;
    if (n) {
        const uint32_t base = lbase;
        for (uint32_t e = threadIdx.x; e < n; e += 1024) {
            uint32_t g = base + e;
            if (g < CAP) cand[(size_t)p * CAP + g] = stage[e];
        }
    }
}

__global__ __launch_bounds__(1024) void select_kernel(
    const float* __restrict__ boxes, const unsigned long long* __restrict__ cand,
    const uint32_t* __restrict__ cand_cnt, uint32_t* __restrict__ cand_idx,
    float* __restrict__ cand_score, double* __restrict__ boxdata,
    float* __restrict__ screen)
{
    const int p = blockIdx.x;
    const int b = p / NCLS;
    const int tid = threadIdx.x;
    __shared__ unsigned long long skey[CAP];
    const int cnt = min((int)cand_cnt[p], CAP);
    skey[tid] = (tid < cnt) ? cand[(size_t)p * CAP + tid] : 0ull;
    __syncthreads();

    // bitonic sort, one slot per thread, overall descending
    for (int k2 = 2; k2 <= CAP; k2 <<= 1)
        for (int j = k2 >> 1; j > 0; j >>= 1) {
            int ixj = tid ^ j;
            if (ixj > tid) {
                unsigned long long a = skey[tid], c = skey[ixj];
                bool up = ((tid & k2) == 0);
                if (up ? (a < c) : (a > c)) { skey[tid] = c; skey[ixj] = a; }
            }
            __syncthreads();
        }

    // epilogue: top-512 decode + f64 geometry + f32 screen
    if (tid >= PRE) return;
    unsigned long long key = skey[tid];
    double* D = boxdata + (size_t)(p * PRE + tid) * 20;
    float* S = screen + (size_t)(p * PRE + tid) * 8;
    if (key == 0ull) {                     // defensive: can't happen normally
        cand_idx[p * PRE + tid] = 0;
        cand_score[p * PRE + tid] = -1.0f;
        #pragma unroll
        for (int m = 0; m < 20; ++m) D[m] = 0.0;
        #pragma unroll
        for (int m = 0; m < 8; ++m) S[m] = 0.0f;
        return;
    }
    uint32_t idx = ~((uint32_t)key);
    uint32_t ov = (uint32_t)(key >> 32);
    uint32_t ub = (ov & 0x80000000u) ? (ov ^ 0x80000000u) : ~ov;
    float sc = __uint_as_float(ub);
    cand_idx[p * PRE + tid] = idx;
    cand_score[p * PRE + tid] = sc;

    const float* bp = boxes + ((size_t)b * NPTS + idx) * 7;
    double x = bp[0], y = bp[1], z = bp[2];
    double dx = bp[3], dy = bp[4], dz = bp[5], r = bp[6];
    double c = cos(r), s = sin(r);
    double hx = 0.5 * dx, hy = 0.5 * dy;
    double zlo = z - 0.5 * dz, zhi = z + 0.5 * dz;
    double rad = sqrt(hx * hx + hy * hy);
    D[0] = x; D[1] = y; D[2] = c; D[3] = s; D[4] = hx; D[5] = hy;
    D[6] = zlo; D[7] = zhi; D[8] = dx * dy * dz; D[9] = rad;
    const double lxs[4] = { hx, -hx, -hx,  hx };
    const double lys[4] = { hy,  hy, -hy, -hy };
    #pragma unroll
    for (int m = 0; m < 4; ++m) {
        D[10 + m] = x + lxs[m] * c - lys[m] * s;
        D[14 + m] = y + lxs[m] * s + lys[m] * c;
    }
    S[0] = (float)x; S[1] = (float)y; S[2] = (float)zlo; S[3] = (float)zhi;
    S[4] = (float)rad; S[5] = 0.0f; S[6] = 0.0f; S[7] = 0.0f;
}

// Fused screen + exact IoU. One wave per (prob, cell, row): wave owns mask
// word (prob,i,wj) exclusively and ALWAYS stores it (even 0) -> mask needs
// no pre-zero. Lower-triangle words stay garbage: bits there mark columns
// j<i, which the greedy scan has already passed -- provably no effect.
// The <=24 candidate points live in lanes 0-23, so the sort/reductions run
// on 32-lane groups (15 bitonic stages, 5-step butterflies) not 64.
__global__ __launch_bounds__(256) void iou_fused_kernel(
    const float* __restrict__ screen, const double* __restrict__ boxdata,
    unsigned long long* __restrict__ mask)
{
    const int W = blockIdx.x * 4 + (threadIdx.x >> 6);
    const int lane = threadIdx.x & 63;
    const int prob = W / WAVES_PER_PROB;
    int t = W - prob * WAVES_PER_PROB;
    int cell = t >> 6, r = t & 63;
    int wi = 0;
    while (cell >= 8 - wi) { cell -= 8 - wi; ++wi; }
    const int wj = wi + cell;
    const int bi = wi * 64 + r;
    const int j = wj * 64 + lane;

    bool surv = false;
    {
        const float* SA = screen + (size_t)(prob * PRE + bi) * 8; // wave-uniform
        const float* SB = screen + (size_t)(prob * PRE + j) * 8;
        if (j > bi) {
            float4 a4 = *(const float4*)SA;           // x,y,zlo,zhi
            float4 b4 = *(const float4*)SB;
            float hz = fminf(a4.w, b4.w) - fmaxf(a4.z, b4.z);
            if (hz > 0.0f) {
                float ddx = a4.x - b4.x, ddy = a4.y - b4.y;
                float rs = SA[4] + SB[4] + 0.01f;
                surv = (ddx * ddx + ddy * ddy <= rs * rs);
            }
        }
    }
    unsigned long long sm = __ballot(surv);   // wave-uniform survivor set
    unsigned long long supw = 0ull;
    const double* A = boxdata + (size_t)(prob * PRE + bi) * 20;

    while (sm) {
        int jb = __ffsll(sm) - 1;
        sm &= sm - 1ull;
        const int bj = wj * 64 + jb;
        const double* B = boxdata + (size_t)(prob * PRE + bj) * 20;

        // lane owns one candidate point: 0-3 A-corners, 4-7 B-corners,
        // 8-23 edge intersections (reference construction order)
        double PX = 0.0, PY = 0.0;
        bool valid = false;
        if (lane < 8) {
            const double* S = (lane < 4) ? A : B;
            const double* O = (lane < 4) ? B : A;
            int m = lane & 3;
            PX = S[10 + m]; PY = S[14 + m];
            double rx = PX - O[0], ry = PY - O[1];
            double u =  rx * O[2] + ry * O[3];
            double v = -rx * O[3] + ry * O[2];
            valid = (fabs(u) <= O[4] + 1e-5) && (fabs(v) <= O[5] + 1e-5);
        } else if (lane < 24) {
            int e = lane - 8, m = e >> 2, nn = e & 3;
            double ax = A[10 + m], ay = A[14 + m];
            double rax = A[10 + ((m + 1) & 3)] - ax;
            double ray = A[14 + ((m + 1) & 3)] - ay;
            double bx = B[10 + nn], by = B[14 + nn];
            double rbx = B[10 + ((nn + 1) & 3)] - bx;
            double rby = B[14 + ((nn + 1) & 3)] - by;
            double d = rax * rby - ray * rbx;
            if (fabs(d) > 1e-8) {
                double qx = bx - ax, qy = by - ay;
                double tt = (qx * rby - qy * rbx) / d;
                double uu = (qx * ray - qy * rax) / d;
                valid = (tt >= 0.0 && tt <= 1.0 && uu >= 0.0 && uu <= 1.0);
                PX = ax + tt * rax; PY = ay + tt * ray;
            }
        }
        if (!valid) { PX = 0.0; PY = 0.0; }

        unsigned long long bal = __ballot(valid);  // valid only in lanes 0-23
        int cnt = __popcll(bal);
        double sx = PX, sy = PY;          // invalid lanes contribute 0
        #pragma unroll
        for (int off = 16; off; off >>= 1) {       // 32-group butterfly
            sx += __shfl_xor(sx, off);
            sy += __shfl_xor(sy, off);
        }
        int cdiv = cnt > 0 ? cnt : 1;     // ref: / max(cnt, 1)
        double cxc = sx / cdiv, cyc = sy / cdiv;

        double ang = valid ? atan2(PY - cyc, PX - cxc) : 1e9;
        int sidx = lane;                  // construction order == ref slots

        // 32-lane bitonic sort asc by (ang, sidx) == numpy stable argsort
        #pragma unroll
        for (int k = 2; k <= 32; k <<= 1) {
            #pragma unroll
            for (int jj = k >> 1; jj > 0; jj >>= 1) {
                double oang = __shfl_xor(ang, jj);
                double opx  = __shfl_xor(PX, jj);
                double opy  = __shfl_xor(PY, jj);
                int    oidx = __shfl_xor(sidx, jj);
                bool iLow = (lane & jj) == 0;
                bool dirUp = (lane & k) == 0;
                bool mineFirst = (ang < oang) || (ang == oang && sidx < oidx);
                bool keepMine = (mineFirst == (iLow == dirUp));
                if (!keepMine) { ang = oang; PX = opx; PY = opy; sidx = oidx; }
            }
        }

        // centered shoelace over sorted lanes [0, cnt)  (cnt <= 24 < 32)
        double nxp = __shfl(PX, (lane + 1) & 31);
        double nyp = __shfl(PY, (lane + 1) & 31);
        double fx  = __shfl(PX, 0);
        double fy  = __shfl(PY, 0);
        bool last = (lane == cnt - 1);
        double qx = last ? fx : nxp, qy = last ? fy : nyp;
        double contrib = 0.0;
        if (lane < cnt)
            contrib = (PX - cxc) * (qy - cyc) - (PY - cyc) * (qx - cxc);
        #pragma unroll
        for (int off = 16; off; off >>= 1) contrib += __shfl_xor(contrib, off);
        double inter = (cnt >= 3) ? 0.5 * fabs(contrib) : 0.0;

        if (lane == 0) {
            double zt = fmin(A[7], B[7]);
            double zb = fmax(A[6], B[6]);
            double hz = zt - zb;
            bool sup = false;
            if (hz > 0.0) {
                double i3 = inter * hz;
                double den = A[8] + B[8] - i3;
                if (den < 1e-8) den = 1e-8;
                sup = (i3 / den) > (double)NMS_TH;
            }
            if (sup) supw |= 1ull << jb;
        }
    }

    if (lane == 0)
        mask[(size_t)(prob * PRE + bi) * 8 + wj] = supw;   // exclusive word
}

__global__ __launch_bounds__(256) void nms_out_kernel(
    const float* __restrict__ boxes, const uint32_t* __restrict__ cand_idx,
    const float* __restrict__ cand_score,
    const unsigned long long* __restrict__ mask, float* __restrict__ out)
{
    const int p = blockIdx.x;
    const int b = p / NCLS, k = p % NCLS;
    const int tid = threadIdx.x;

    __shared__ unsigned long long smask[PRE * 8];   // 32 KB
    __shared__ float sscore[PRE];
    __shared__ int slist[POST];
    __shared__ int scnt;

    for (int w = tid; w < PRE * 8; w += 256)
        smask[w] = mask[(size_t)p * PRE * 8 + w];
    for (int i = tid; i < PRE; i += 256)
        sscore[i] = cand_score[p * PRE + i];
    __syncthreads();

    // Wave-parallel greedy scan; early break at c==POST. Garbage bits in
    // lower-triangle mask words only mark columns j<i (already processed)
    // and cannot change any keep decision.
    if (tid < 64) {
        const int lane = tid;
        uint32_t supbits = 0;
        int c = 0;
        for (int i = 0; i < PRE; ++i) {
            uint32_t sb = (uint32_t)__shfl((int)supbits, i & 63);
            bool sup_i = (sb >> (i >> 6)) & 1u;
            float sc = sscore[i];                      // LDS broadcast
            bool keep = (sc >= SCORE_TH) && !sup_i;    // wave-uniform
            if (keep) {
                if (lane == 0) slist[c] = i;
                ++c;
                if (c >= POST) break;
                #pragma unroll
                for (int w = 0; w < 8; ++w) {
                    unsigned long long m = smask[i * 8 + w];  // broadcast
                    supbits |= (uint32_t)((m >> lane) & 1ull) << w;
                }
            }
        }
        if (lane == 0) scnt = c;
    }
    __syncthreads();

    const int cnt = scnt;
    for (int t = tid; t < POST; t += 256) {
        int row = b * (NCLS * POST) + k * POST + t;          // 0..599
        float* ob = out + (size_t)row * 7;
        float* os = out + (size_t)NB * NCLS * POST * 7 + row;
        float* ol = out + (size_t)NB * NCLS * POST * 7 + (size_t)NB * NCLS * POST + row;
        if (t < cnt) {
            int r = slist[t];
            uint32_t idx = cand_idx[p * PRE + r];
            const float* bp = boxes + ((size_t)b * NPTS + idx) * 7;
            #pragma unroll
            for (int c7 = 0; c7 < 7; ++c7) ob[c7] = bp[c7];
            *os = sscore[r];
            *ol = (float)(k + 1);
        } else {
            #pragma unroll
            for (int c7 = 0; c7 < 7; ++c7) ob[c7] = 0.0f;
            *os = 0.0f;
            *ol = 0.0f;
        }
    }
}

extern "C" void kernel_launch(void* const* d_in, const int* in_sizes, int n_in,
                              void* d_out, int out_size, void* d_ws, size_t ws_size,
                              hipStream_t stream)
{
    (void)in_sizes; (void)n_in; (void)out_size; (void)ws_size;
    const float* cls   = (const float*)d_in[0];   // (2,100000,3) f32
    const float* boxes = (const float*)d_in[1];   // (2,100000,7) f32
    float* out = (float*)d_out;

    char* ws = (char*)d_ws;
    uint32_t* pivots      = (uint32_t*)(ws);
    uint32_t* cand_cnt    = (uint32_t*)(ws + 64);
    unsigned long long* mask = (unsigned long long*)(ws + 128);
    unsigned long long* cand = (unsigned long long*)(ws + 196736);
    uint32_t* cand_idx    = (uint32_t*)(ws + 245888);
    float*    cand_score  = (float*)   (ws + 258176);
    double*   boxdata     = (double*)  (ws + 270464);
    float*    screen      = (float*)   (ws + 761984);
    float*    sf          = (float*)   (ws + 860288);
    uint32_t* hist_part   = (uint32_t*)(ws + 3260288);

    // No memset: hist uses per-block partials, cand_cnt zeroed by pivot,
    // mask fully written (upper triangle) by iou_fused.

    hipLaunchKernelGGL(hist_kernel, dim3(NB * BPP), dim3(1024), 0, stream,
                       cls, sf, hist_part);
    hipLaunchKernelGGL(pivot_kernel, dim3(NPROB), dim3(512), 0, stream,
                       hist_part, pivots, cand_cnt);
    hipLaunchKernelGGL(compact_kernel, dim3(NPROB * BPP), dim3(1024), 0, stream,
                       cls, sf, pivots, cand_cnt, cand);
    hipLaunchKernelGGL(select_kernel, dim3(NPROB), dim3(1024), 0, stream,
                       boxes, cand, cand_cnt, cand_idx, cand_score, boxdata, screen);
    hipLaunchKernelGGL(iou_fused_kernel, dim3(NPROB * WAVES_PER_PROB / 4),
                       dim3(256), 0, stream, screen, boxdata, mask);
    hipLaunchKernelGGL(nms_out_kernel, dim3(NPROB), dim3(256), 0, stream,
                       boxes, cand_idx, cand_score, mask, out);
}